// Round 8
// baseline (33073.361 us; speedup 1.0000x reference)
//
#include <hip/hip_runtime.h>
#include <stdint.h>

#define TT 512
#define BB 64
#define DD 512

// ---------- helpers ----------
__device__ __forceinline__ float bfl(uint32_t u){ return __uint_as_float(u << 16); }
__device__ __forceinline__ float bfh(uint32_t u){ return __uint_as_float(u & 0xffff0000u); }
__device__ __forceinline__ float bf2f(uint16_t u){ return __uint_as_float(((uint32_t)u) << 16); }
__device__ __forceinline__ float u2f(uint32_t u){ return __uint_as_float(u); }
__device__ __forceinline__ uint16_t f2bf(float f){
  uint32_t u = __float_as_uint(f);
  u += 0x7fffu + ((u >> 16) & 1u);
  return (uint16_t)(u >> 16);
}
__device__ __forceinline__ uint32_t packbf(float a, float b){
  return (uint32_t)f2bf(a) | ((uint32_t)f2bf(b) << 16);
}
// clamp-free graceful forms: p=0 -> -1/0; p=inf -> 1/1
__device__ __forceinline__ float fast_tanh(float x){
  float p = __builtin_amdgcn_exp2f(x * 2.8853900817779268f);
  return __builtin_fmaf(-2.f, __builtin_amdgcn_rcpf(p + 1.f), 1.f);
}
__device__ __forceinline__ float fast_sig(float x){
  float p = __builtin_amdgcn_exp2f(x * 1.4426950408889634f);
  return 1.f - __builtin_amdgcn_rcpf(p + 1.f);
}

#define SCOPE_AG __HIP_MEMORY_SCOPE_AGENT

// ---- state WRITES: write-through to L3 (L2-bypass). Reads are PLAIN (L2-cached);
// freshness comes from the acquire-fence (L1+L2 invalidate) at each barrier exit.
__device__ __forceinline__ void st32_coh(uint32_t* p, uint32_t v){
  asm volatile("global_store_dword %0, %1, off sc0 sc1" :: "v"(p), "v"(v) : "memory");
}
__device__ __forceinline__ void drain_vm(){
  asm volatile("s_waitcnt vmcnt(0)" ::: "memory");
}
__device__ __forceinline__ void spin_neq(int* p, int v){
  while (__hip_atomic_load(p, __ATOMIC_RELAXED, SCOPE_AG) == v)
    __builtin_amdgcn_s_sleep(1);
}
__device__ __forceinline__ void acq_inv(){   // one per barrier exit, wave 0 only
  __builtin_amdgcn_fence(__ATOMIC_ACQUIRE, "agent");
}

// Two-level grid barrier, 256 WGs; exit invalidates L1/L2 so plain reads see L3.
__device__ void gridbar(int* bar){
  drain_vm();
  __syncthreads();
  if (threadIdx.x == 0){
    int x = blockIdx.x & 7;
    int* scnt = bar + x * 32;
    int* sgen = bar + (8 + x) * 32;
    int* mcnt = bar + 16 * 32;
    int* mgen = bar + 17 * 32;
    int g = __hip_atomic_load(sgen, __ATOMIC_RELAXED, SCOPE_AG);
    int old = __hip_atomic_fetch_add(scnt, 1, __ATOMIC_RELAXED, SCOPE_AG);
    if (old == 31){
      __hip_atomic_store(scnt, 0, __ATOMIC_RELAXED, SCOPE_AG);
      int gm = __hip_atomic_load(mgen, __ATOMIC_RELAXED, SCOPE_AG);
      int om = __hip_atomic_fetch_add(mcnt, 1, __ATOMIC_RELAXED, SCOPE_AG);
      if (om == 7){
        __hip_atomic_store(mcnt, 0, __ATOMIC_RELAXED, SCOPE_AG);
        __hip_atomic_fetch_add(mgen, 1, __ATOMIC_RELAXED, SCOPE_AG);
      } else {
        spin_neq(mgen, gm);
      }
      __hip_atomic_fetch_add(sgen, 1, __ATOMIC_RELAXED, SCOPE_AG);
    } else {
      spin_neq(sgen, g);
    }
    acq_inv();
  }
  __syncthreads();
}

// 4-member group barrier (WGs sharing batch element b: wg = b + 64k).
__device__ __forceinline__ void groupbar(int* bar, int gid){
  drain_vm();
  __syncthreads();
  if (threadIdx.x == 0){
    int* c = bar + (32 + gid) * 32;
    int* g = bar + (96 + gid) * 32;
    int gv = __hip_atomic_load(g, __ATOMIC_RELAXED, SCOPE_AG);
    int old = __hip_atomic_fetch_add(c, 1, __ATOMIC_RELAXED, SCOPE_AG);
    if (old == 3){
      __hip_atomic_store(c, 0, __ATOMIC_RELAXED, SCOPE_AG);
      __hip_atomic_fetch_add(g, 1, __ATOMIC_RELAXED, SCOPE_AG);
    } else {
      spin_neq(g, gv);
    }
    acq_inv();
  }
  __syncthreads();
}

// ---------- K0: conversions / init ----------
__global__ void prep_kernel(
  const float* __restrict__ att_w1,
  const float* __restrict__ l0_bih, const float* __restrict__ l0_bhh,
  const float* __restrict__ l1_bih, const float* __restrict__ l1_bhh,
  uint32_t* __restrict__ wsT, float* __restrict__ b0c, float* __restrict__ b1c,
  int* __restrict__ bar)
{
  int stride = gridDim.x * blockDim.x;
  int i0 = blockIdx.x * blockDim.x + threadIdx.x;
  for (int i = i0; i < 256*512; i += stride){
    int k2 = i >> 9, j = i & 511;
    wsT[i] = packbf(att_w1[(size_t)j*1024 + 2*k2], att_w1[(size_t)j*1024 + 2*k2 + 1]);
  }
  for (int i = i0; i < 2048; i += stride){
    b0c[i] = l0_bih[i] + l0_bhh[i];
    b1c[i] = l1_bih[i] + l1_bhh[i];
  }
  for (int i = i0; i < 8192; i += stride) bar[i] = 0;
}

// ---------- K0b: x[t][b][k] f32 -> xt[t][k2][b] bf16-pairs ----------
__global__ __launch_bounds__(256) void xpose_x(const float* __restrict__ x,
                                               uint32_t* __restrict__ xt)
{
  __shared__ float tile[64][65];
  int t = blockIdx.x, kb = blockIdx.y;
  int r = threadIdx.x >> 2, c0 = (threadIdx.x & 3) * 16;
  const float* src = x + ((size_t)t*64 + r)*512 + kb*64 + c0;
  #pragma unroll
  for (int i = 0; i < 16; i += 4)
    *(float4*)&tile[r][c0 + i] = *(const float4*)(src + i);
  __syncthreads();
  int b = threadIdx.x & 63, k2l0 = threadIdx.x >> 6;
  for (int k2l = k2l0; k2l < 32; k2l += 4)
    xt[((size_t)t*256 + kb*32 + k2l)*64 + b] = packbf(tile[b][k2l*2], tile[b][k2l*2+1]);
}

// ---------- K2b: hctx[t][b][d] -> hctxT[b][d][t] (bf16) ----------
__global__ __launch_bounds__(256) void xpose_h(const uint16_t* __restrict__ hctx,
                                               uint16_t* __restrict__ hctxT)
{
  __shared__ uint16_t tile[64][72];
  int b = blockIdx.x, tb = blockIdx.y, db = blockIdx.z;
  int tl = threadIdx.x >> 2, c0 = (threadIdx.x & 3) * 16;
  const uint16_t* src = hctx + ((size_t)(tb*64 + tl)*64 + b)*512 + db*64 + c0;
  *(uint4*)&tile[tl][c0]     = *(const uint4*)src;
  *(uint4*)&tile[tl][c0 + 8] = *(const uint4*)(src + 8);
  __syncthreads();
  int dl = threadIdx.x >> 2, t0 = (threadIdx.x & 3) * 16;
  uint16_t tmp[16];
  #pragma unroll
  for (int i = 0; i < 16; ++i) tmp[i] = tile[t0 + i][dl];
  uint16_t* dst = hctxT + ((size_t)b*512 + db*64 + dl)*512 + tb*64 + t0;
  *(uint4*)dst       = *(uint4*)tmp;
  *(uint4*)(dst + 8) = *(uint4*)(tmp + 8);
}

// ---------- K1/K3: C = A @ B^T + bias ----------
// OMODE: 0 = f32 row-major, 1 = bf16 row-major, 2 = bf16 ph-layout [kq*64+b][tt][128]
template<bool ABF, int OMODE>
__global__ __launch_bounds__(256) void gemm_bias(
  const void* __restrict__ A_, const float* __restrict__ B0, int ldb0,
  const float* __restrict__ B1, int ldb1, int nsplit,
  const float* __restrict__ bias0, const float* __restrict__ bias1,
  void* __restrict__ C_, int M, int N, int K)
{
  __shared__ float As[16][132];
  __shared__ float Bs[16][68];
  const int bm = blockIdx.x * 128, bn = blockIdx.y * 64;
  const int tid = threadIdx.x;
  const int m0 = (tid >> 4) * 8, n0 = (tid & 15) * 4;
  float acc[8][4] = {};
  for (int k0 = 0; k0 < K; k0 += 16){
    {
      int r = tid >> 1, c = (tid & 1) * 8;
      if (ABF){
        const uint16_t* ap = (const uint16_t*)A_ + (size_t)(bm + r) * K + k0 + c;
        uint4 v = *(const uint4*)ap;
        const uint16_t* pv = (const uint16_t*)&v;
        #pragma unroll
        for (int i = 0; i < 8; ++i) As[c + i][r] = bf2f(pv[i]);
      } else {
        const float* ap = (const float*)A_ + (size_t)(bm + r) * K + k0 + c;
        float4 v0 = *(const float4*)ap, v1 = *(const float4*)(ap + 4);
        As[c+0][r] = v0.x; As[c+1][r] = v0.y; As[c+2][r] = v0.z; As[c+3][r] = v0.w;
        As[c+4][r] = v1.x; As[c+5][r] = v1.y; As[c+6][r] = v1.z; As[c+7][r] = v1.w;
      }
    }
    {
      int n = tid >> 2, cc = (tid & 3) * 4;
      int gn = bn + n;
      const float* bp = (gn < nsplit) ? (B0 + (size_t)gn * ldb0 + k0 + cc)
                                      : (B1 + (size_t)(gn - nsplit) * ldb1 + k0 + cc);
      float4 v = *(const float4*)bp;
      Bs[cc+0][n] = v.x; Bs[cc+1][n] = v.y; Bs[cc+2][n] = v.z; Bs[cc+3][n] = v.w;
    }
    __syncthreads();
    #pragma unroll
    for (int k = 0; k < 16; ++k){
      float a[8], bv[4];
      #pragma unroll
      for (int i = 0; i < 8; ++i) a[i] = As[k][m0 + i];
      #pragma unroll
      for (int j = 0; j < 4; ++j) bv[j] = Bs[k][n0 + j];
      #pragma unroll
      for (int i = 0; i < 8; ++i)
        #pragma unroll
        for (int j = 0; j < 4; ++j) acc[i][j] += a[i] * bv[j];
    }
    __syncthreads();
  }
  #pragma unroll
  for (int i = 0; i < 8; ++i){
    int gm = bm + m0 + i;
    #pragma unroll
    for (int j = 0; j < 4; ++j){
      int gn = bn + n0 + j;
      float bias = (gn < nsplit) ? bias0[gn] : bias1[gn - nsplit];
      float v = acc[i][j] + bias;
      if (OMODE == 0){
        ((float*)C_)[(size_t)gm * N + gn] = v;
      } else if (OMODE == 1){
        ((uint16_t*)C_)[(size_t)gm * N + gn] = f2bf(v);
      } else {
        // gm = tt*64 + b, gn = d -> [ (d>>7)*64 + b ][ tt ][ d&127 ]
        size_t idx = ((size_t)((gn >> 7) * 64 + (gm & 63)) * 512 + (gm >> 6)) * 128
                   + (gn & 127);
        ((uint16_t*)C_)[idx] = f2bf(v);
      }
    }
  }
}

// ---------- K2: bi-RNN scan ----------
__global__ __launch_bounds__(512) void rnn_scan(
  const float* __restrict__ xp, const float* __restrict__ whf,
  const float* __restrict__ whb, const float* __restrict__ bhf,
  const float* __restrict__ bhb, uint16_t* __restrict__ hctx)
{
  __shared__ float hbuf[256];
  __shared__ float partial[512];
  const int wg = blockIdx.x, dir = wg >> 6, b = wg & 63, tid = threadIdx.x;
  const int j = tid & 255, half = tid >> 8;
  const float* wh = dir ? whb : whf;
  const float bj = (dir ? bhb : bhf)[j];
  uint32_t wreg[64];
  #pragma unroll
  for (int m = 0; m < 64; ++m){
    int k = half * 128 + m * 2;
    wreg[m] = packbf(wh[j * 256 + k], wh[j * 256 + k + 1]);
  }
  if (tid < 256) hbuf[tid] = 0.f;
  __syncthreads();
  for (int step = 0; step < TT; ++step){
    int t = dir ? (TT - 1 - step) : step;
    float acc = 0.f;
    const float* hb = hbuf + half * 128;
    #pragma unroll 16
    for (int m = 0; m < 64; ++m){
      uint32_t w = wreg[m];
      acc += bfl(w) * hb[m * 2] + bfh(w) * hb[m * 2 + 1];
    }
    partial[tid] = acc;
    __syncthreads();
    if (tid < 256){
      float v = partial[tid] + partial[tid + 256]
              + xp[(size_t)(t * 64 + b) * 512 + dir * 256 + j] + bj;
      v = fast_tanh(v);
      hbuf[j] = v;
      hctx[(size_t)(t * 64 + b) * 512 + dir * 256 + j] = f2bf(v);
    }
    __syncthreads();
  }
}

// ---------- LSTM inner dot: 16 k2 rows of [128 k2][64 b] tiles ----------
__device__ __forceinline__ void lstm_dot(
  const uint32_t* __restrict__ tXl, const uint32_t* __restrict__ tSl,
  const float* __restrict__ wl, int kk0, int b, int ul, int q8, float* acc)
{
  #pragma unroll 8
  for (int pp = 0; pp < 8; ++pp){
    int k2l = q8 * 16 + pp * 2;
    uint32_t xv0 = tXl[k2l * 64 + b];
    uint32_t xv1 = tXl[(k2l + 1) * 64 + b];
    uint32_t sv0 = tSl[k2l * 64 + b];
    uint32_t sv1 = tSl[(k2l + 1) * 64 + b];
    float x0 = bfl(xv0), x1 = bfh(xv0), x2 = bfl(xv1), x3 = bfh(xv1);
    float s0 = bfl(sv0), s1 = bfh(sv0), s2 = bfl(sv1), s3 = bfh(sv1);
    const float* wb = wl + ul * 512 + kk0 + k2l * 2;
    #pragma unroll
    for (int g = 0; g < 4; ++g){
      float4 wi = *(const float4*)(wb + g * 1024);
      float4 wh = *(const float4*)(wb + 4096 + g * 1024);
      acc[g] += x0 * wi.x + x1 * wi.y + x2 * wi.z + x3 * wi.w
              + s0 * wh.x + s1 * wh.y + s2 * wh.z + s3 * wh.w;
    }
  }
}

// ---------- LSTM gate phase (1024 threads); all reads plain (post-fence fresh) ----------
__device__ __forceinline__ void lstm_phase(
  const uint32_t* __restrict__ xin,   // [256 k2][64 b] pairs
  const uint32_t* __restrict__ hin,   // [256 k2][64 b] pairs
  const float* __restrict__ wl, const float* __restrict__ bias8,
  float& cs0, float& cs1,
  uint32_t* __restrict__ hog,         // [256][64] pair out, row = wgid (sc write)
  uint32_t* __restrict__ hogT,        // optional [64 b][256 k2] transposed copy
  float* __restrict__ outp,           // optional out + t*32768
  uint32_t* tX, uint32_t* tS, float* part, float* glds,
  int u0, int tid, int wgid)
{
  const int b = tid & 63, ul = (tid >> 6) & 1, q8 = tid >> 7;
  float acc[4] = {0.f, 0.f, 0.f, 0.f};
  #pragma unroll 1
  for (int ch = 0; ch < 2; ++ch){
    {
      const uint32_t* xs = xin + ch * 8192;
      const uint32_t* hs = hin + ch * 8192;
      uint4 a0 = *(const uint4*)(xs + tid * 4);
      uint4 a1 = *(const uint4*)(xs + 4096 + tid * 4);
      uint4 c0 = *(const uint4*)(hs + tid * 4);
      uint4 c1 = *(const uint4*)(hs + 4096 + tid * 4);
      *(uint4*)(tX + tid * 4)        = a0;
      *(uint4*)(tX + 4096 + tid * 4) = a1;
      *(uint4*)(tS + tid * 4)        = c0;
      *(uint4*)(tS + 4096 + tid * 4) = c1;
    }
    __syncthreads();
    lstm_dot(tX, tS, wl, ch * 256, b, ul, q8, acc);
    __syncthreads();
  }
  #pragma unroll
  for (int g = 0; g < 4; ++g) part[((g * 2 + ul) * 8 + q8) * 64 + b] = acc[g];
  __syncthreads();
  if (tid < 512){
    int g = tid >> 7, uu = (tid >> 6) & 1, bb = tid & 63;
    float s = bias8[g * 2 + uu];
    #pragma unroll
    for (int i = 0; i < 8; ++i) s += part[((g * 2 + uu) * 8 + i) * 64 + bb];
    glds[(g * 2 + uu) * 64 + bb] = s;
  }
  __syncthreads();
  if (tid < 64){
    float gi0 = glds[0 * 64 + tid], gi1 = glds[1 * 64 + tid];
    float gf0 = glds[2 * 64 + tid], gf1 = glds[3 * 64 + tid];
    float gg0 = glds[4 * 64 + tid], gg1 = glds[5 * 64 + tid];
    float go0 = glds[6 * 64 + tid], go1 = glds[7 * 64 + tid];
    float c0 = fast_sig(gf0) * cs0 + fast_sig(gi0) * fast_tanh(gg0);
    float c1 = fast_sig(gf1) * cs1 + fast_sig(gi1) * fast_tanh(gg1);
    cs0 = c0; cs1 = c1;
    float h0v = fast_sig(go0) * fast_tanh(c0);
    float h1v = fast_sig(go1) * fast_tanh(c1);
    uint32_t pr = packbf(h0v, h1v);
    st32_coh(hog + wgid * 64 + tid, pr);
    if (hogT) st32_coh(hogT + tid * 256 + wgid, pr);
    if (outp) *(float2*)(outp + (size_t)tid * 512 + u0) = make_float2(h0v, h1v);
  }
  __syncthreads();
}

// ---------- K4: persistent fused main scan (256 WGs x 1024 threads, coop) ----------
// Per step: A0+A1 -> peg store -> LSTM1(t-1) [hides groupbar] -> groupbar ->
//           A2+A3 -> s store -> S1 -> LSTM0(t) -> S2
__global__ __launch_bounds__(1024) void main_loop(
  const uint16_t* __restrict__ ph,     // [kq*64+b][tt][128] bf16
  const uint16_t* __restrict__ hctxT,  // [b][d][tt]
  const uint32_t* __restrict__ xt,     // [t][256][64] pairs
  const uint32_t* __restrict__ wsT,    // [256 k2][512 j] pairs
  const float* __restrict__ w0i, const float* __restrict__ w0h,
  const float* __restrict__ w1i, const float* __restrict__ w1h,
  const float* __restrict__ b0c, const float* __restrict__ b1c,
  const float* __restrict__ attw2, const float* __restrict__ attb2,
  uint32_t* __restrict__ peg,          // [4 kq][64 b][512 tt] f32 partial-e
  uint32_t* __restrict__ sg, uint32_t* __restrict__ h0g,
  uint32_t* __restrict__ h0gT,         // [64 b][256 k2] pairs
  uint32_t* __restrict__ h1ga, uint32_t* __restrict__ h1gb,
  float* __restrict__ out, int* bar)
{
  __shared__ __align__(16) float wl0[16 * 512];        // 32KB persistent L0 weights
  __shared__ __align__(16) float wl1[16 * 512];        // 32KB persistent L1 weights
  __shared__ __align__(16) uint32_t tX[128 * 64];      // 32KB LSTM arena A
  __shared__ __align__(16) uint32_t tS[128 * 64];      // 32KB LSTM arena B
  __shared__ float glds[512];
  // dedicated attention arena — survives across LSTM1 interleave
  __shared__ float hldf[512];
  __shared__ float qloc[128];
  __shared__ float eldf[8 * 66];
  __shared__ float qpart[128 * 9];
  __shared__ float spart[512 * 3];
  __shared__ float w2loc[128];
  __shared__ float w2s[2];
  __shared__ float bias0l[8], bias1l[8];
  __shared__ float zsh[1];

  const int wg = blockIdx.x, tid = threadIdx.x;
  const int b_att = wg & 63, kq = wg >> 6;
  const int u0 = wg * 2;
  float* spart2 = spart;   // reuse after spart consumed
  float* part = (float*)tX;

  // ---- one-time LDS loads ----
  {
    int r = tid >> 6, c = (tid & 63) * 8;
    int rr = r & 7, g = rr >> 1, uu = rr & 1;
    const float* s0 = ((r < 8) ? w0i : w0h) + ((size_t)(g * 512 + u0 + uu)) * 512 + c;
    *(float4*)(wl0 + r * 512 + c)     = *(const float4*)s0;
    *(float4*)(wl0 + r * 512 + c + 4) = *(const float4*)(s0 + 4);
    const float* s1 = ((r < 8) ? w1i : w1h) + ((size_t)(g * 512 + u0 + uu)) * 512 + c;
    *(float4*)(wl1 + r * 512 + c)     = *(const float4*)s1;
    *(float4*)(wl1 + r * 512 + c + 4) = *(const float4*)(s1 + 4);
  }
  if (tid < 128) w2loc[tid] = -2.f * attw2[kq * 128 + tid];
  if (tid >= 128 && tid < 130){
    int h = tid - 128; float s = 0.f;
    for (int i = 0; i < 64; ++i) s += attw2[kq * 128 + h * 64 + i];
    w2s[h] = s;
  }
  if (tid < 8){
    int g = tid >> 1, uu = tid & 1;
    bias0l[tid] = b0c[g * 512 + u0 + uu];
    bias1l[tid] = b1c[g * 512 + u0 + uu];
  }
  const float b2s = attb2[0];
  float c0s0 = 0.f, c0s1 = 0.f, c1s0 = 0.f, c1s1 = 0.f;

  // zero shared-state buffers (visible after first gridbar's fence)
  {
    int idx = wg * 1024 + tid;
    if (idx < 256 * 64){
      st32_coh(sg + idx, 0); st32_coh(h0g + idx, 0);
      st32_coh(h1ga + idx, 0); st32_coh(h1gb + idx, 0);
    }
  }
  __syncthreads();

  #pragma unroll 1
  for (int t = 0; t < TT; ++t){
    if (t > 0){
      // ---- A0: stage h0[b_att] (coalesced h0gT, plain) + q quarter GEMV ----
      if (tid < 256){
        uint32_t v = h0gT[b_att * 256 + tid];
        hldf[tid * 2] = bfl(v); hldf[tid * 2 + 1] = bfh(v);
      }
      __syncthreads();
      {
        int jl = tid & 127, kseg = tid >> 7;
        const uint32_t* wp = wsT + (size_t)(kseg * 32) * 512 + kq * 128 + jl;
        float acc = 0.f;
        #pragma unroll 8
        for (int i = 0; i < 32; ++i){
          uint32_t w = wp[(size_t)i * 512];
          acc += bfl(w) * hldf[(kseg * 32 + i) * 2] + bfh(w) * hldf[(kseg * 32 + i) * 2 + 1];
        }
        qpart[jl * 9 + kseg] = acc;
      }
      __syncthreads();
      if (tid < 128){
        float s = 0.f;
        #pragma unroll
        for (int i = 0; i < 8; ++i) s += qpart[tid * 9 + i];
        qloc[tid] = s;
      }
      __syncthreads();
      // ---- A1: partial scores over ALL 512 tt, contiguous per-WG ph slice ----
      {
        int ttl = tid >> 1, dseg = tid & 1;
        const uint16_t* pb = ph + (((size_t)(kq * 64 + b_att) * 512) + ttl) * 128
                                + dseg * 64;
        uint4 v[8];
        #pragma unroll
        for (int i = 0; i < 8; ++i) v[i] = *(const uint4*)(pb + i * 8);
        const float* qp = qloc + dseg * 64;
        const float* wp = w2loc + dseg * 64;
        float acc = 0.f;
        #pragma unroll
        for (int i = 0; i < 8; ++i){
          const uint16_t* pv = (const uint16_t*)&v[i];
          #pragma unroll
          for (int j = 0; j < 8; ++j){
            float z = bf2f(pv[j]) + qp[i * 8 + j];
            float p = __builtin_amdgcn_exp2f(z * 2.8853900817779268f);
            acc = __builtin_fmaf(wp[i * 8 + j], __builtin_amdgcn_rcpf(p + 1.f), acc);
          }
        }
        spart[ttl * 3 + dseg] = acc;
      }
      __syncthreads();
      if (tid < 512){   // contiguous 2KB store per WG
        float s = spart[tid * 3] + spart[tid * 3 + 1] + w2s[0] + w2s[1];
        st32_coh(peg + ((size_t)(kq * 64 + b_att)) * 512 + tid, __float_as_uint(s));
      }
      // ---- LSTM1 for step t-1: overlaps peg drain + sibling skew ----
      {
        int tau = t - 1;
        const uint32_t* h1rd = (tau & 1) ? h1gb : h1ga;
        uint32_t* h1wr = (tau & 1) ? h1ga : h1gb;
        lstm_phase(h0g, h1rd, wl1, bias1l, c1s0, c1s1,
                   h1wr, nullptr, out + (size_t)tau * (64 * 512),
                   tX, tS, part, glds, u0, tid, wg);
      }
      groupbar(bar, b_att);
      // ---- A2: e finalize (plain loads, post-fence) + Z ----
      if (tid < 512){
        const uint32_t* pg = peg + (size_t)b_att * 512 + tid;
        float s = u2f(pg[0]) + u2f(pg[32768]) + u2f(pg[65536]) + u2f(pg[98304]) + b2s;
        float e = fast_tanh(s);
        eldf[(tid >> 6) * 66 + (tid & 63)] = __builtin_amdgcn_exp2f(e * 1.4426950408889634f);
      }
      __syncthreads();
      if (tid < 64){
        float zp = 0.f;
        #pragma unroll
        for (int k = 0; k < 8; ++k) zp += eldf[k * 66 + tid];
        #pragma unroll
        for (int m = 32; m; m >>= 1) zp += __shfl_xor(zp, m);
        if (tid == 0) zsh[0] = __builtin_amdgcn_rcpf(zp);
      }
      // ---- A3: ctx partial (own 128-d slice, all tt) ----
      {
        int dl = tid >> 3, tseg = tid & 7;
        const uint16_t* hb = hctxT + ((size_t)b_att * 512 + kq * 128 + dl) * 512 + tseg * 64;
        const float* ep = eldf + tseg * 66;
        float acc = 0.f;
        #pragma unroll 2
        for (int i = 0; i < 8; ++i){
          uint4 v = *(const uint4*)(hb + i * 8);
          const uint16_t* pv = (const uint16_t*)&v;
          #pragma unroll
          for (int j = 0; j < 8; ++j)
            acc = __builtin_fmaf(ep[i * 8 + j], bf2f(pv[j]), acc);
        }
        __syncthreads();     // spart consumed; safe to reuse
        spart2[dl * 9 + tseg] = acc;
      }
      __syncthreads();
      if (tid < 64){
        float cv0 = 0.f, cv1 = 0.f;
        #pragma unroll
        for (int i = 0; i < 8; ++i){
          cv0 += spart2[(2 * tid) * 9 + i];
          cv1 += spart2[(2 * tid + 1) * 9 + i];
        }
        float rz = zsh[0];
        float s0 = hldf[kq * 128 + 2 * tid]     + cv0 * rz;
        float s1 = hldf[kq * 128 + 2 * tid + 1] + cv1 * rz;
        st32_coh(sg + (kq * 64 + tid) * 64 + b_att, packbf(s0, s1));
      }
    }
    gridbar(bar);   // S1: s(t) visible grid-wide (fence -> plain reads fresh)
    lstm_phase(xt + (size_t)t * 16384, sg, wl0, bias0l, c0s0, c0s1,
               h0g, h0gT, nullptr, tX, tS, part, glds, u0, tid, wg);
    gridbar(bar);   // S2: h0(t) visible grid-wide
  }
  // epilogue: LSTM1 for step 511 (511 & 1 = 1 -> read h1gb)
  lstm_phase(h0g, h1gb, wl1, bias1l, c1s0, c1s1,
             h1ga, nullptr, out + (size_t)(TT - 1) * (64 * 512),
             tX, tS, part, glds, u0, tid, wg);
}

// ---------- host ----------
extern "C" void kernel_launch(void* const* d_in, const int* in_sizes, int n_in,
                              void* d_out, int out_size, void* d_ws, size_t ws_size,
                              hipStream_t stream)
{
  (void)in_sizes; (void)n_in; (void)out_size; (void)ws_size;
  const float* x       = (const float*)d_in[0];
  const float* rnn_wif = (const float*)d_in[1];
  const float* rnn_whf = (const float*)d_in[2];
  const float* rnn_bif = (const float*)d_in[3];
  const float* rnn_bhf = (const float*)d_in[4];
  const float* rnn_wib = (const float*)d_in[5];
  const float* rnn_whb = (const float*)d_in[6];
  const float* rnn_bib = (const float*)d_in[7];
  const float* rnn_bhb = (const float*)d_in[8];
  const float* att_w1  = (const float*)d_in[9];
  const float* att_b1  = (const float*)d_in[10];
  const float* att_w2  = (const float*)d_in[11];
  const float* att_b2  = (const float*)d_in[12];
  const float* l0_wih  = (const float*)d_in[13];
  const float* l0_whh  = (const float*)d_in[14];
  const float* l0_bih  = (const float*)d_in[15];
  const float* l0_bhh  = (const float*)d_in[16];
  const float* l1_wih  = (const float*)d_in[17];
  const float* l1_whh  = (const float*)d_in[18];
  const float* l1_bih  = (const float*)d_in[19];
  const float* l1_bhh  = (const float*)d_in[20];
  float* out = (float*)d_out;

  char* p = (char*)d_ws;
  auto take = [&](size_t bytes){ char* r = p; p += (bytes + 255) & ~(size_t)255; return r; };
  uint16_t* ph    = (uint16_t*)take((size_t)TT * BB * DD * 2);
  uint16_t* hctx  = (uint16_t*)take((size_t)TT * BB * DD * 2);
  uint16_t* hctxT = (uint16_t*)take((size_t)TT * BB * DD * 2);
  uint32_t* xt    = (uint32_t*)take((size_t)TT * 256 * 64 * 4);
  uint32_t* wsT   = (uint32_t*)take(256 * 512 * 4);
  float* b0c = (float*)take(2048 * 4);
  float* b1c = (float*)take(2048 * 4);
  uint32_t* peg = (uint32_t*)take((size_t)4 * 64 * 512 * 4);
  uint32_t* sg   = (uint32_t*)take(256 * 64 * 4);
  uint32_t* h0g  = (uint32_t*)take(256 * 64 * 4);
  uint32_t* h0gT = (uint32_t*)take(64 * 256 * 4);
  uint32_t* h1ga = (uint32_t*)take(256 * 64 * 4);
  uint32_t* h1gb = (uint32_t*)take(256 * 64 * 4);
  int* bar = (int*)take(8192 * 4);

  float* xp = out;   // d_out doubles as RNN input-projection buffer

  prep_kernel<<<256, 256, 0, stream>>>(att_w1, l0_bih, l0_bhh, l1_bih, l1_bhh,
                                       wsT, b0c, b1c, bar);
  xpose_x<<<dim3(512, 8), 256, 0, stream>>>(x, xt);

  gemm_bias<false,0><<<dim3(256, 8), 256, 0, stream>>>(
      x, rnn_wif, 512, rnn_wib, 512, 256, rnn_bif, rnn_bib, (void*)xp, 32768, 512, 512);

  rnn_scan<<<128, 512, 0, stream>>>(xp, rnn_whf, rnn_whb, rnn_bhf, rnn_bhb, hctx);

  xpose_h<<<dim3(64, 8, 8), 256, 0, stream>>>(hctx, hctxT);

  gemm_bias<true,2><<<dim3(256, 8), 256, 0, stream>>>(
      hctx, att_w1 + 512, 1024, nullptr, 1024, 512, att_b1, nullptr, (void*)ph, 32768, 512, 512);

  {
    const uint16_t* ph_c = ph; const uint16_t* hctxT_c = hctxT;
    const uint32_t* xt_c = xt; const uint32_t* wsT_c = wsT;
    const float *w0i = l0_wih, *w0h = l0_whh, *w1i = l1_wih, *w1h = l1_whh;
    const float *b0c_c = b0c, *b1c_c = b1c, *aw2 = att_w2, *ab2 = att_b2;
    float *out_ = out;
    uint32_t *peg_ = peg, *sg_ = sg, *h0g_ = h0g, *h0gT_ = h0gT, *h1ga_ = h1ga, *h1gb_ = h1gb;
    int* bar_ = bar;
    void* args[] = {
      (void*)&ph_c, (void*)&hctxT_c, (void*)&xt_c, (void*)&wsT_c,
      (void*)&w0i, (void*)&w0h, (void*)&w1i, (void*)&w1h,
      (void*)&b0c_c, (void*)&b1c_c, (void*)&aw2, (void*)&ab2,
      (void*)&peg_, (void*)&sg_, (void*)&h0g_, (void*)&h0gT_, (void*)&h1ga_, (void*)&h1gb_,
      (void*)&out_, (void*)&bar_
    };
    hipLaunchCooperativeKernel((void*)main_loop, dim3(256), dim3(1024), args, 0, stream);
  }
}

// Round 9
// 27888.895 us; speedup vs baseline: 1.1859x; 1.1859x over previous
//
#include <hip/hip_runtime.h>
#include <stdint.h>

#define TT 512
#define BB 64
#define DD 512

// ---------- helpers ----------
__device__ __forceinline__ float bfl(uint32_t u){ return __uint_as_float(u << 16); }
__device__ __forceinline__ float bfh(uint32_t u){ return __uint_as_float(u & 0xffff0000u); }
__device__ __forceinline__ float bf2f(uint16_t u){ return __uint_as_float(((uint32_t)u) << 16); }
__device__ __forceinline__ float u2f(uint32_t u){ return __uint_as_float(u); }
__device__ __forceinline__ uint16_t f2bf(float f){
  uint32_t u = __float_as_uint(f);
  u += 0x7fffu + ((u >> 16) & 1u);
  return (uint16_t)(u >> 16);
}
__device__ __forceinline__ uint32_t packbf(float a, float b){
  return (uint32_t)f2bf(a) | ((uint32_t)f2bf(b) << 16);
}
// clamp-free graceful forms: p=0 -> -1/0; p=inf -> 1/1
__device__ __forceinline__ float fast_tanh(float x){
  float p = __builtin_amdgcn_exp2f(x * 2.8853900817779268f);
  return __builtin_fmaf(-2.f, __builtin_amdgcn_rcpf(p + 1.f), 1.f);
}
__device__ __forceinline__ float fast_sig(float x){
  float p = __builtin_amdgcn_exp2f(x * 1.4426950408889634f);
  return 1.f - __builtin_amdgcn_rcpf(p + 1.f);
}

// ---------- fp8 e4m3fn pack/unpack (HW on gfx950; SW fallback) ----------
#if __has_builtin(__builtin_amdgcn_cvt_pk_f32_fp8) && __has_builtin(__builtin_amdgcn_cvt_pk_fp8_f32)
#define HWFP8 1
typedef float f32x2_t __attribute__((ext_vector_type(2)));
#endif

__device__ __forceinline__ float fp8_dec1(uint32_t v){
  uint32_t em = v & 0x7f, sg = (v >> 7) << 31;
  float nf = __uint_as_float(sg | (((em >> 3) + 120) << 23) | ((em & 7) << 20));
  float sf = __uint_as_float(sg | 0x3B000000u) * (float)(em & 7);   // m * 2^-9, signed
  return (em >> 3) ? nf : sf;
}
__device__ __forceinline__ uint32_t fp8_enc1(float f){
  uint32_t u = __float_as_uint(f);
  uint32_t sg = (u >> 31) << 7;
  uint32_t e = (u >> 23) & 0xff;
  if (e >= 121){                               // |f| >= 2^-6: normal fp8
    u += 0x7ffff + ((u >> 20) & 1);            // RTE to 3 mantissa bits
    e = (u >> 23) & 0xff;
    uint32_t m = (u >> 20) & 7;
    uint32_t e8 = e - 120;
    if (e8 > 15){ e8 = 15; m = 6; }            // clamp to 448
    return sg | (e8 << 3) | m;
  }
  float af = __uint_as_float(u & 0x7fffffffu);
  uint32_t m = (uint32_t)__builtin_rintf(af * 512.f);
  if (m >= 8) return sg | 0x08u;
  return sg | m;
}
__device__ __forceinline__ void fp8x4_dec(uint32_t w, float* o){
#ifdef HWFP8
  f32x2_t lo = __builtin_amdgcn_cvt_pk_f32_fp8((int)w, false);
  f32x2_t hi = __builtin_amdgcn_cvt_pk_f32_fp8((int)w, true);
  o[0] = lo.x; o[1] = lo.y; o[2] = hi.x; o[3] = hi.y;
#else
  o[0] = fp8_dec1(w & 0xff); o[1] = fp8_dec1((w >> 8) & 0xff);
  o[2] = fp8_dec1((w >> 16) & 0xff); o[3] = fp8_dec1(w >> 24);
#endif
}
__device__ __forceinline__ uint32_t fp8x4_enc(float a, float b, float c, float d){
#ifdef HWFP8
  int u = __builtin_amdgcn_cvt_pk_fp8_f32(a, b, 0, false);
  u = __builtin_amdgcn_cvt_pk_fp8_f32(c, d, u, true);
  return (uint32_t)u;
#else
  return fp8_enc1(a) | (fp8_enc1(b) << 8) | (fp8_enc1(c) << 16) | (fp8_enc1(d) << 24);
#endif
}

#define SCOPE_AG __HIP_MEMORY_SCOPE_AGENT

// ---- coherent (L2-bypass, L3 coherence point) accessors; ALWAYS full wait ----
__device__ __forceinline__ uint32_t ld32_coh(const uint32_t* p){
  uint32_t r;
  asm volatile("global_load_dword %0, %1, off sc0 sc1\n\ts_waitcnt vmcnt(0)"
               : "=&v"(r) : "v"(p) : "memory");
  return r;
}
__device__ __forceinline__ void ld32x4_coh(const uint32_t* p0, const uint32_t* p1,
                                           const uint32_t* p2, const uint32_t* p3,
                                           uint32_t& a, uint32_t& b,
                                           uint32_t& c, uint32_t& d){
  asm volatile("global_load_dword %0, %4, off sc0 sc1\n\t"
               "global_load_dword %1, %5, off sc0 sc1\n\t"
               "global_load_dword %2, %6, off sc0 sc1\n\t"
               "global_load_dword %3, %7, off sc0 sc1\n\t"
               "s_waitcnt vmcnt(0)"
               : "=&v"(a), "=&v"(b), "=&v"(c), "=&v"(d)
               : "v"(p0), "v"(p1), "v"(p2), "v"(p3) : "memory");
}
__device__ __forceinline__ void ld16x2_coh2(const void* p0, const void* p1,
                                            uint4& a, uint4& b){
  asm volatile("global_load_dwordx4 %0, %2, off sc0 sc1\n\t"
               "global_load_dwordx4 %1, %3, off sc0 sc1\n\t"
               "s_waitcnt vmcnt(0)"
               : "=&v"(a), "=&v"(b) : "v"(p0), "v"(p1) : "memory");
}
__device__ __forceinline__ void ld16x4_coh4(const void* p0, const void* p1,
                                            const void* p2, const void* p3,
                                            uint4& a, uint4& b, uint4& c, uint4& d){
  asm volatile("global_load_dwordx4 %0, %4, off sc0 sc1\n\t"
               "global_load_dwordx4 %1, %5, off sc0 sc1\n\t"
               "global_load_dwordx4 %2, %6, off sc0 sc1\n\t"
               "global_load_dwordx4 %3, %7, off sc0 sc1\n\t"
               "s_waitcnt vmcnt(0)"
               : "=&v"(a), "=&v"(b), "=&v"(c), "=&v"(d)
               : "v"(p0), "v"(p1), "v"(p2), "v"(p3) : "memory");
}
__device__ __forceinline__ void st32_coh(uint32_t* p, uint32_t v){
  asm volatile("global_store_dword %0, %1, off sc0 sc1" :: "v"(p), "v"(v) : "memory");
}
__device__ __forceinline__ void stf_coh(float* p, float v){
  st32_coh((uint32_t*)p, __float_as_uint(v));
}
__device__ __forceinline__ void drain_vm(){
  asm volatile("s_waitcnt vmcnt(0)" ::: "memory");
}
__device__ __forceinline__ void spin_neq(int* p, int v){
  while (__hip_atomic_load(p, __ATOMIC_RELAXED, SCOPE_AG) == v)
    __builtin_amdgcn_s_sleep(1);
}

// Two-level grid barrier, 256 WGs, relaxed agent-scope atomics (proven r2/r3/r7).
__device__ void gridbar(int* bar){
  drain_vm();
  __syncthreads();
  if (threadIdx.x == 0){
    int x = blockIdx.x & 7;
    int* scnt = bar + x * 32;
    int* sgen = bar + (8 + x) * 32;
    int* mcnt = bar + 16 * 32;
    int* mgen = bar + 17 * 32;
    int g = __hip_atomic_load(sgen, __ATOMIC_RELAXED, SCOPE_AG);
    int old = __hip_atomic_fetch_add(scnt, 1, __ATOMIC_RELAXED, SCOPE_AG);
    if (old == 31){
      __hip_atomic_store(scnt, 0, __ATOMIC_RELAXED, SCOPE_AG);
      int gm = __hip_atomic_load(mgen, __ATOMIC_RELAXED, SCOPE_AG);
      int om = __hip_atomic_fetch_add(mcnt, 1, __ATOMIC_RELAXED, SCOPE_AG);
      if (om == 7){
        __hip_atomic_store(mcnt, 0, __ATOMIC_RELAXED, SCOPE_AG);
        __hip_atomic_fetch_add(mgen, 1, __ATOMIC_RELAXED, SCOPE_AG);
      } else {
        spin_neq(mgen, gm);
      }
      __hip_atomic_fetch_add(sgen, 1, __ATOMIC_RELAXED, SCOPE_AG);
    } else {
      spin_neq(sgen, g);
    }
  }
  __syncthreads();
}

// 4-member group barrier (WGs sharing batch element b: wg = b + 64k).
__device__ __forceinline__ void groupbar(int* bar, int gid){
  drain_vm();
  __syncthreads();
  if (threadIdx.x == 0){
    int* c = bar + (32 + gid) * 32;
    int* g = bar + (96 + gid) * 32;
    int gv = __hip_atomic_load(g, __ATOMIC_RELAXED, SCOPE_AG);
    int old = __hip_atomic_fetch_add(c, 1, __ATOMIC_RELAXED, SCOPE_AG);
    if (old == 3){
      __hip_atomic_store(c, 0, __ATOMIC_RELAXED, SCOPE_AG);
      __hip_atomic_fetch_add(g, 1, __ATOMIC_RELAXED, SCOPE_AG);
    } else {
      spin_neq(g, gv);
    }
  }
  __syncthreads();
}

// ---------- K0: conversions / init ----------
__global__ void prep_kernel(
  const float* __restrict__ att_w1,
  const float* __restrict__ l0_bih, const float* __restrict__ l0_bhh,
  const float* __restrict__ l1_bih, const float* __restrict__ l1_bhh,
  uint32_t* __restrict__ wsT, float* __restrict__ b0c, float* __restrict__ b1c,
  int* __restrict__ bar)
{
  int stride = gridDim.x * blockDim.x;
  int i0 = blockIdx.x * blockDim.x + threadIdx.x;
  for (int i = i0; i < 256*512; i += stride){
    int k2 = i >> 9, j = i & 511;
    wsT[i] = packbf(att_w1[(size_t)j*1024 + 2*k2], att_w1[(size_t)j*1024 + 2*k2 + 1]);
  }
  for (int i = i0; i < 2048; i += stride){
    b0c[i] = l0_bih[i] + l0_bhh[i];
    b1c[i] = l1_bih[i] + l1_bhh[i];
  }
  for (int i = i0; i < 8192; i += stride) bar[i] = 0;
}

// ---------- K0b: x[t][b][k] f32 -> xt[t][k2][b] bf16-pairs ----------
__global__ __launch_bounds__(256) void xpose_x(const float* __restrict__ x,
                                               uint32_t* __restrict__ xt)
{
  __shared__ float tile[64][65];
  int t = blockIdx.x, kb = blockIdx.y;
  int r = threadIdx.x >> 2, c0 = (threadIdx.x & 3) * 16;
  const float* src = x + ((size_t)t*64 + r)*512 + kb*64 + c0;
  #pragma unroll
  for (int i = 0; i < 16; i += 4)
    *(float4*)&tile[r][c0 + i] = *(const float4*)(src + i);
  __syncthreads();
  int b = threadIdx.x & 63, k2l0 = threadIdx.x >> 6;
  for (int k2l = k2l0; k2l < 32; k2l += 4)
    xt[((size_t)t*256 + kb*32 + k2l)*64 + b] = packbf(tile[b][k2l*2], tile[b][k2l*2+1]);
}

// ---------- K2b: hctx[t][b][d] -> h8T[b][d][t] (fp8 e4m3) ----------
__global__ __launch_bounds__(256) void xpose_h(const uint16_t* __restrict__ hctx,
                                               uint8_t* __restrict__ h8T)
{
  __shared__ uint16_t tile[64][72];
  int b = blockIdx.x, tb = blockIdx.y, db = blockIdx.z;
  int tl = threadIdx.x >> 2, c0 = (threadIdx.x & 3) * 16;
  const uint16_t* src = hctx + ((size_t)(tb*64 + tl)*64 + b)*512 + db*64 + c0;
  *(uint4*)&tile[tl][c0]     = *(const uint4*)src;
  *(uint4*)&tile[tl][c0 + 8] = *(const uint4*)(src + 8);
  __syncthreads();
  int dl = threadIdx.x >> 2, t0 = (threadIdx.x & 3) * 16;
  uint16_t tmp[16];
  #pragma unroll
  for (int i = 0; i < 16; ++i) tmp[i] = tile[t0 + i][dl];
  uint32_t o[4];
  #pragma unroll
  for (int k = 0; k < 4; ++k)
    o[k] = fp8x4_enc(bf2f(tmp[k*4]), bf2f(tmp[k*4+1]), bf2f(tmp[k*4+2]), bf2f(tmp[k*4+3]));
  uint8_t* dst = h8T + ((size_t)b*512 + db*64 + dl)*512 + tb*64 + t0;
  *(uint4*)dst = make_uint4(o[0], o[1], o[2], o[3]);
}

// ---------- K1/K3: C = A @ B^T + bias ----------
// OMODE: 0 = f32 row-major, 2 = fp8 ph-layout [kq*64+b][tt][128]
template<bool ABF, int OMODE>
__global__ __launch_bounds__(256) void gemm_bias(
  const void* __restrict__ A_, const float* __restrict__ B0, int ldb0,
  const float* __restrict__ B1, int ldb1, int nsplit,
  const float* __restrict__ bias0, const float* __restrict__ bias1,
  void* __restrict__ C_, int M, int N, int K)
{
  __shared__ float As[16][132];
  __shared__ float Bs[16][68];
  const int bm = blockIdx.x * 128, bn = blockIdx.y * 64;
  const int tid = threadIdx.x;
  const int m0 = (tid >> 4) * 8, n0 = (tid & 15) * 4;
  float acc[8][4] = {};
  for (int k0 = 0; k0 < K; k0 += 16){
    {
      int r = tid >> 1, c = (tid & 1) * 8;
      if (ABF){
        const uint16_t* ap = (const uint16_t*)A_ + (size_t)(bm + r) * K + k0 + c;
        uint4 v = *(const uint4*)ap;
        const uint16_t* pv = (const uint16_t*)&v;
        #pragma unroll
        for (int i = 0; i < 8; ++i) As[c + i][r] = bf2f(pv[i]);
      } else {
        const float* ap = (const float*)A_ + (size_t)(bm + r) * K + k0 + c;
        float4 v0 = *(const float4*)ap, v1 = *(const float4*)(ap + 4);
        As[c+0][r] = v0.x; As[c+1][r] = v0.y; As[c+2][r] = v0.z; As[c+3][r] = v0.w;
        As[c+4][r] = v1.x; As[c+5][r] = v1.y; As[c+6][r] = v1.z; As[c+7][r] = v1.w;
      }
    }
    {
      int n = tid >> 2, cc = (tid & 3) * 4;
      int gn = bn + n;
      const float* bp = (gn < nsplit) ? (B0 + (size_t)gn * ldb0 + k0 + cc)
                                      : (B1 + (size_t)(gn - nsplit) * ldb1 + k0 + cc);
      float4 v = *(const float4*)bp;
      Bs[cc+0][n] = v.x; Bs[cc+1][n] = v.y; Bs[cc+2][n] = v.z; Bs[cc+3][n] = v.w;
    }
    __syncthreads();
    #pragma unroll
    for (int k = 0; k < 16; ++k){
      float a[8], bv[4];
      #pragma unroll
      for (int i = 0; i < 8; ++i) a[i] = As[k][m0 + i];
      #pragma unroll
      for (int j = 0; j < 4; ++j) bv[j] = Bs[k][n0 + j];
      #pragma unroll
      for (int i = 0; i < 8; ++i)
        #pragma unroll
        for (int j = 0; j < 4; ++j) acc[i][j] += a[i] * bv[j];
    }
    __syncthreads();
  }
  #pragma unroll
  for (int i = 0; i < 8; ++i){
    int gm = bm + m0 + i;
    if (OMODE == 2){
      float vv[4];
      #pragma unroll
      for (int j = 0; j < 4; ++j){
        int gn = bn + n0 + j;
        float bias = (gn < nsplit) ? bias0[gn] : bias1[gn - nsplit];
        vv[j] = acc[i][j] + bias;
      }
      int gn0 = bn + n0;   // 4-aligned, all 4 within one 128-block
      size_t idx = ((size_t)((gn0 >> 7) * 64 + (gm & 63)) * 512 + (gm >> 6)) * 128
                 + (gn0 & 127);
      *(uint32_t*)((uint8_t*)C_ + idx) = fp8x4_enc(vv[0], vv[1], vv[2], vv[3]);
    } else {
      #pragma unroll
      for (int j = 0; j < 4; ++j){
        int gn = bn + n0 + j;
        float bias = (gn < nsplit) ? bias0[gn] : bias1[gn - nsplit];
        ((float*)C_)[(size_t)gm * N + gn] = acc[i][j] + bias;
      }
    }
  }
}

// ---------- K2: bi-RNN scan ----------
__global__ __launch_bounds__(512) void rnn_scan(
  const float* __restrict__ xp, const float* __restrict__ whf,
  const float* __restrict__ whb, const float* __restrict__ bhf,
  const float* __restrict__ bhb, uint16_t* __restrict__ hctx)
{
  __shared__ float hbuf[256];
  __shared__ float partial[512];
  const int wg = blockIdx.x, dir = wg >> 6, b = wg & 63, tid = threadIdx.x;
  const int j = tid & 255, half = tid >> 8;
  const float* wh = dir ? whb : whf;
  const float bj = (dir ? bhb : bhf)[j];
  uint32_t wreg[64];
  #pragma unroll
  for (int m = 0; m < 64; ++m){
    int k = half * 128 + m * 2;
    wreg[m] = packbf(wh[j * 256 + k], wh[j * 256 + k + 1]);
  }
  if (tid < 256) hbuf[tid] = 0.f;
  __syncthreads();
  for (int step = 0; step < TT; ++step){
    int t = dir ? (TT - 1 - step) : step;
    float acc = 0.f;
    const float* hb = hbuf + half * 128;
    #pragma unroll 16
    for (int m = 0; m < 64; ++m){
      uint32_t w = wreg[m];
      acc += bfl(w) * hb[m * 2] + bfh(w) * hb[m * 2 + 1];
    }
    partial[tid] = acc;
    __syncthreads();
    if (tid < 256){
      float v = partial[tid] + partial[tid + 256]
              + xp[(size_t)(t * 64 + b) * 512 + dir * 256 + j] + bj;
      v = fast_tanh(v);
      hbuf[j] = v;
      hctx[(size_t)(t * 64 + b) * 512 + dir * 256 + j] = f2bf(v);
    }
    __syncthreads();
  }
}

// ---------- LSTM inner dot: 16 k2 rows of [128 k2][64 b] tiles ----------
__device__ __forceinline__ void lstm_dot(
  const uint32_t* __restrict__ tXl, const uint32_t* __restrict__ tSl,
  const float* __restrict__ wl, int kk0, int b, int ul, int q8, float* acc)
{
  #pragma unroll 8
  for (int pp = 0; pp < 8; ++pp){
    int k2l = q8 * 16 + pp * 2;
    uint32_t xv0 = tXl[k2l * 64 + b];
    uint32_t xv1 = tXl[(k2l + 1) * 64 + b];
    uint32_t sv0 = tSl[k2l * 64 + b];
    uint32_t sv1 = tSl[(k2l + 1) * 64 + b];
    float x0 = bfl(xv0), x1 = bfh(xv0), x2 = bfl(xv1), x3 = bfh(xv1);
    float s0 = bfl(sv0), s1 = bfh(sv0), s2 = bfl(sv1), s3 = bfh(sv1);
    const float* wb = wl + ul * 512 + kk0 + k2l * 2;
    #pragma unroll
    for (int g = 0; g < 4; ++g){
      float4 wi = *(const float4*)(wb + g * 1024);
      float4 wh = *(const float4*)(wb + 4096 + g * 1024);
      acc[g] += x0 * wi.x + x1 * wi.y + x2 * wi.z + x3 * wi.w
              + s0 * wh.x + s1 * wh.y + s2 * wh.z + s3 * wh.w;
    }
  }
}

// ---------- LSTM gate phase (1024 threads); lane-consecutive 16B staging ----------
template<bool XCOH>
__device__ __forceinline__ void lstm_phase(
  const uint32_t* __restrict__ xin,   // [256 k2][64 b] pairs (plain if !XCOH)
  const uint32_t* __restrict__ hin,   // [256 k2][64 b] pairs (coherent)
  const float* __restrict__ wl, const float* __restrict__ bias8,
  float& cs0, float& cs1,
  uint32_t* __restrict__ hog,         // [256][64] pair out, row = wgid
  uint32_t* __restrict__ hogT,        // optional [64 b][256 k2] transposed copy
  float* __restrict__ outp,           // optional out + t*32768
  uint32_t* tX, uint32_t* tS, float* part, float* glds,
  int u0, int tid, int wgid)
{
  const int b = tid & 63, ul = (tid >> 6) & 1, q8 = tid >> 7;
  float acc[4] = {0.f, 0.f, 0.f, 0.f};
  #pragma unroll 1
  for (int ch = 0; ch < 2; ++ch){
    {
      const uint32_t* xs = xin + ch * 8192;
      const uint32_t* hs = hin + ch * 8192;
      uint4 a0, a1, c0, c1;
      if (XCOH){
        ld16x4_coh4(xs + tid * 4, xs + 4096 + tid * 4,
                    hs + tid * 4, hs + 4096 + tid * 4, a0, a1, c0, c1);
      } else {
        a0 = *(const uint4*)(xs + tid * 4);
        a1 = *(const uint4*)(xs + 4096 + tid * 4);
        ld16x2_coh2(hs + tid * 4, hs + 4096 + tid * 4, c0, c1);
      }
      *(uint4*)(tX + tid * 4)        = a0;
      *(uint4*)(tX + 4096 + tid * 4) = a1;
      *(uint4*)(tS + tid * 4)        = c0;
      *(uint4*)(tS + 4096 + tid * 4) = c1;
    }
    __syncthreads();
    lstm_dot(tX, tS, wl, ch * 256, b, ul, q8, acc);
    __syncthreads();
  }
  #pragma unroll
  for (int g = 0; g < 4; ++g) part[((g * 2 + ul) * 8 + q8) * 64 + b] = acc[g];
  __syncthreads();
  if (tid < 512){
    int g = tid >> 7, uu = (tid >> 6) & 1, bb = tid & 63;
    float s = bias8[g * 2 + uu];
    #pragma unroll
    for (int i = 0; i < 8; ++i) s += part[((g * 2 + uu) * 8 + i) * 64 + bb];
    glds[(g * 2 + uu) * 64 + bb] = s;
  }
  __syncthreads();
  if (tid < 64){
    float gi0 = glds[0 * 64 + tid], gi1 = glds[1 * 64 + tid];
    float gf0 = glds[2 * 64 + tid], gf1 = glds[3 * 64 + tid];
    float gg0 = glds[4 * 64 + tid], gg1 = glds[5 * 64 + tid];
    float go0 = glds[6 * 64 + tid], go1 = glds[7 * 64 + tid];
    float c0 = fast_sig(gf0) * cs0 + fast_sig(gi0) * fast_tanh(gg0);
    float c1 = fast_sig(gf1) * cs1 + fast_sig(gi1) * fast_tanh(gg1);
    cs0 = c0; cs1 = c1;
    float h0v = fast_sig(go0) * fast_tanh(c0);
    float h1v = fast_sig(go1) * fast_tanh(c1);
    uint32_t pr = packbf(h0v, h1v);
    st32_coh(hog + wgid * 64 + tid, pr);
    if (hogT) st32_coh(hogT + tid * 256 + wgid, pr);
    if (outp) *(float2*)(outp + (size_t)tid * 512 + u0) = make_float2(h0v, h1v);
  }
  __syncthreads();
}

// ---------- K4: persistent fused main scan (256 WGs x 1024 threads, coop) ----------
// Per step: A0+A1 -> peg store -> LSTM1(t-1) [hides groupbar] -> groupbar ->
//           A2+A3 -> s store -> S1 -> LSTM0(t) -> S2
__global__ __launch_bounds__(1024) void main_loop(
  const uint8_t* __restrict__ ph8,     // [kq*64+b][tt][128] fp8
  const uint8_t* __restrict__ h8T,     // [b][d][tt] fp8
  const uint32_t* __restrict__ xt,     // [t][256][64] bf16 pairs
  const uint32_t* __restrict__ wsT,    // [256 k2][512 j] bf16 pairs
  const float* __restrict__ w0i, const float* __restrict__ w0h,
  const float* __restrict__ w1i, const float* __restrict__ w1h,
  const float* __restrict__ b0c, const float* __restrict__ b1c,
  const float* __restrict__ attw2, const float* __restrict__ attb2,
  uint32_t* __restrict__ peg,          // [4 kq][64 b][512 tt] f32 partial-e
  uint32_t* __restrict__ sg, uint32_t* __restrict__ h0g,
  uint32_t* __restrict__ h0gT,         // [64 b][256 k2] pairs
  uint32_t* __restrict__ h1ga, uint32_t* __restrict__ h1gb,
  float* __restrict__ out, int* bar)
{
  __shared__ __align__(16) float wl0[16 * 512];        // 32KB persistent L0 weights
  __shared__ __align__(16) float wl1[16 * 512];        // 32KB persistent L1 weights
  __shared__ __align__(16) uint32_t tX[128 * 64];      // 32KB LSTM arena A
  __shared__ __align__(16) uint32_t tS[128 * 64];      // 32KB LSTM arena B
  __shared__ float glds[512];
  // dedicated attention arena — survives across LSTM1 interleave
  __shared__ float hldf[512];
  __shared__ float qloc[128];
  __shared__ float eldf[8 * 66];
  __shared__ float qpart[128 * 9];
  __shared__ float spart[512 * 3];
  __shared__ float w2loc[128];
  __shared__ float w2s[2];
  __shared__ float bias0l[8], bias1l[8];
  __shared__ float zsh[1];

  const int wg = blockIdx.x, tid = threadIdx.x;
  const int b_att = wg & 63, kq = wg >> 6;
  const int u0 = wg * 2;
  float* spart2 = spart;   // reuse after spart consumed
  float* part = (float*)tX;

  // ---- one-time LDS loads ----
  {
    int r = tid >> 6, c = (tid & 63) * 8;
    int rr = r & 7, g = rr >> 1, uu = rr & 1;
    const float* s0 = ((r < 8) ? w0i : w0h) + ((size_t)(g * 512 + u0 + uu)) * 512 + c;
    *(float4*)(wl0 + r * 512 + c)     = *(const float4*)s0;
    *(float4*)(wl0 + r * 512 + c + 4) = *(const float4*)(s0 + 4);
    const float* s1 = ((r < 8) ? w1i : w1h) + ((size_t)(g * 512 + u0 + uu)) * 512 + c;
    *(float4*)(wl1 + r * 512 + c)     = *(const float4*)s1;
    *(float4*)(wl1 + r * 512 + c + 4) = *(const float4*)(s1 + 4);
  }
  if (tid < 128) w2loc[tid] = -2.f * attw2[kq * 128 + tid];
  if (tid >= 128 && tid < 130){
    int h = tid - 128; float s = 0.f;
    for (int i = 0; i < 64; ++i) s += attw2[kq * 128 + h * 64 + i];
    w2s[h] = s;
  }
  if (tid < 8){
    int g = tid >> 1, uu = tid & 1;
    bias0l[tid] = b0c[g * 512 + u0 + uu];
    bias1l[tid] = b1c[g * 512 + u0 + uu];
  }
  const float b2s = attb2[0];
  float c0s0 = 0.f, c0s1 = 0.f, c1s0 = 0.f, c1s1 = 0.f;

  // zero shared-state buffers (visible after first gridbar)
  {
    int idx = wg * 1024 + tid;
    if (idx < 256 * 64){
      st32_coh(sg + idx, 0); st32_coh(h0g + idx, 0);
      st32_coh(h1ga + idx, 0); st32_coh(h1gb + idx, 0);
    }
  }
  __syncthreads();

  #pragma unroll 1
  for (int t = 0; t < TT; ++t){
    if (t > 0){
      // ---- A0: stage h0[b_att] (coalesced h0gT) + q quarter GEMV ----
      if (tid < 256){
        uint32_t v = ld32_coh(h0gT + b_att * 256 + tid);
        hldf[tid * 2] = bfl(v); hldf[tid * 2 + 1] = bfh(v);
      }
      __syncthreads();
      {
        int jl = tid & 127, kseg = tid >> 7;
        const uint32_t* wp = wsT + (size_t)(kseg * 32) * 512 + kq * 128 + jl;
        float acc = 0.f;
        #pragma unroll 8
        for (int i = 0; i < 32; ++i){
          uint32_t w = wp[(size_t)i * 512];
          acc += bfl(w) * hldf[(kseg * 32 + i) * 2] + bfh(w) * hldf[(kseg * 32 + i) * 2 + 1];
        }
        qpart[jl * 9 + kseg] = acc;
      }
      __syncthreads();
      if (tid < 128){
        float s = 0.f;
        #pragma unroll
        for (int i = 0; i < 8; ++i) s += qpart[tid * 9 + i];
        qloc[tid] = s;
      }
      __syncthreads();
      // ---- A1: partial scores over ALL 512 tt, contiguous fp8 ph slice ----
      {
        int ttl = tid >> 1, dseg = tid & 1;
        const uint8_t* pb = ph8 + (((size_t)(kq * 64 + b_att) * 512) + ttl) * 128
                                + dseg * 64;
        uint4 vv[4];
        #pragma unroll
        for (int i = 0; i < 4; ++i) vv[i] = ((const uint4*)pb)[i];
        const float* qp = qloc + dseg * 64;
        const float* wp = w2loc + dseg * 64;
        const uint32_t* wu = (const uint32_t*)vv;
        float acc = 0.f;
        #pragma unroll
        for (int i = 0; i < 16; ++i){
          float f4[4];
          fp8x4_dec(wu[i], f4);
          #pragma unroll
          for (int j = 0; j < 4; ++j){
            float z = f4[j] + qp[i * 4 + j];
            float pw = __builtin_amdgcn_exp2f(z * 2.8853900817779268f);
            acc = __builtin_fmaf(wp[i * 4 + j], __builtin_amdgcn_rcpf(pw + 1.f), acc);
          }
        }
        spart[ttl * 3 + dseg] = acc;
      }
      __syncthreads();
      if (tid < 512){   // contiguous 2KB store per WG
        float s = spart[tid * 3] + spart[tid * 3 + 1] + w2s[0] + w2s[1];
        st32_coh(peg + ((size_t)(kq * 64 + b_att)) * 512 + tid, __float_as_uint(s));
      }
      // ---- LSTM1 for step t-1: overlaps peg drain + sibling skew ----
      {
        int tau = t - 1;
        const uint32_t* h1rd = (tau & 1) ? h1gb : h1ga;
        uint32_t* h1wr = (tau & 1) ? h1ga : h1gb;
        lstm_phase<true>(h0g, h1rd, wl1, bias1l, c1s0, c1s1,
                         h1wr, nullptr, out + (size_t)tau * (64 * 512),
                         tX, tS, part, glds, u0, tid, wg);
      }
      groupbar(bar, b_att);
      // ---- A2: e finalize (4 batched coh loads, 1 wait) + Z ----
      if (tid < 512){
        uint32_t e0, e1, e2, e3;
        const uint32_t* pg = peg + (size_t)b_att * 512 + tid;
        ld32x4_coh(pg, pg + 32768, pg + 65536, pg + 98304, e0, e1, e2, e3);
        float s = u2f(e0) + u2f(e1) + u2f(e2) + u2f(e3) + b2s;
        float e = fast_tanh(s);
        eldf[(tid >> 6) * 66 + (tid & 63)] = __builtin_amdgcn_exp2f(e * 1.4426950408889634f);
      }
      __syncthreads();
      if (tid < 64){
        float zp = 0.f;
        #pragma unroll
        for (int k = 0; k < 8; ++k) zp += eldf[k * 66 + tid];
        #pragma unroll
        for (int m = 32; m; m >>= 1) zp += __shfl_xor(zp, m);
        if (tid == 0) zsh[0] = __builtin_amdgcn_rcpf(zp);
      }
      // ---- A3: ctx partial (own 128-d slice, all tt, fp8) ----
      {
        int dl = tid >> 3, tseg = tid & 7;
        const uint8_t* hb = h8T + ((size_t)b_att * 512 + kq * 128 + dl) * 512 + tseg * 64;
        uint4 vv[4];
        #pragma unroll
        for (int i = 0; i < 4; ++i) vv[i] = ((const uint4*)hb)[i];
        const float* ep = eldf + tseg * 66;
        const uint32_t* wu = (const uint32_t*)vv;
        float acc = 0.f;
        #pragma unroll
        for (int i = 0; i < 16; ++i){
          float f4[4];
          fp8x4_dec(wu[i], f4);
          #pragma unroll
          for (int j = 0; j < 4; ++j)
            acc = __builtin_fmaf(ep[i * 4 + j], f4[j], acc);
        }
        __syncthreads();     // spart consumed; safe to reuse
        spart2[dl * 9 + tseg] = acc;
      }
      __syncthreads();
      if (tid < 64){
        float cv0 = 0.f, cv1 = 0.f;
        #pragma unroll
        for (int i = 0; i < 8; ++i){
          cv0 += spart2[(2 * tid) * 9 + i];
          cv1 += spart2[(2 * tid + 1) * 9 + i];
        }
        float rz = zsh[0];
        float s0 = hldf[kq * 128 + 2 * tid]     + cv0 * rz;
        float s1 = hldf[kq * 128 + 2 * tid + 1] + cv1 * rz;
        st32_coh(sg + (kq * 64 + tid) * 64 + b_att, packbf(s0, s1));
      }
    }
    gridbar(bar);   // S1: s(t) visible grid-wide
    lstm_phase<false>(xt + (size_t)t * 16384, sg, wl0, bias0l, c0s0, c0s1,
                      h0g, h0gT, nullptr, tX, tS, part, glds, u0, tid, wg);
    gridbar(bar);   // S2: h0(t) visible grid-wide
  }
  // epilogue: LSTM1 for step 511 (511 & 1 = 1 -> read h1gb)
  lstm_phase<true>(h0g, h1gb, wl1, bias1l, c1s0, c1s1,
                   h1ga, nullptr, out + (size_t)(TT - 1) * (64 * 512),
                   tX, tS, part, glds, u0, tid, wg);
}

// ---------- host ----------
extern "C" void kernel_launch(void* const* d_in, const int* in_sizes, int n_in,
                              void* d_out, int out_size, void* d_ws, size_t ws_size,
                              hipStream_t stream)
{
  (void)in_sizes; (void)n_in; (void)out_size; (void)ws_size;
  const float* x       = (const float*)d_in[0];
  const float* rnn_wif = (const float*)d_in[1];
  const float* rnn_whf = (const float*)d_in[2];
  const float* rnn_bif = (const float*)d_in[3];
  const float* rnn_bhf = (const float*)d_in[4];
  const float* rnn_wib = (const float*)d_in[5];
  const float* rnn_whb = (const float*)d_in[6];
  const float* rnn_bib = (const float*)d_in[7];
  const float* rnn_bhb = (const float*)d_in[8];
  const float* att_w1  = (const float*)d_in[9];
  const float* att_b1  = (const float*)d_in[10];
  const float* att_w2  = (const float*)d_in[11];
  const float* att_b2  = (const float*)d_in[12];
  const float* l0_wih  = (const float*)d_in[13];
  const float* l0_whh  = (const float*)d_in[14];
  const float* l0_bih  = (const float*)d_in[15];
  const float* l0_bhh  = (const float*)d_in[16];
  const float* l1_wih  = (const float*)d_in[17];
  const float* l1_whh  = (const float*)d_in[18];
  const float* l1_bih  = (const float*)d_in[19];
  const float* l1_bhh  = (const float*)d_in[20];
  float* out = (float*)d_out;

  char* p = (char*)d_ws;
  auto take = [&](size_t bytes){ char* r = p; p += (bytes + 255) & ~(size_t)255; return r; };
  uint8_t*  ph8   = (uint8_t*)take((size_t)TT * BB * DD);
  uint16_t* hctx  = (uint16_t*)take((size_t)TT * BB * DD * 2);
  uint8_t*  h8T   = (uint8_t*)take((size_t)TT * BB * DD);
  uint32_t* xt    = (uint32_t*)take((size_t)TT * 256 * 64 * 4);
  uint32_t* wsT   = (uint32_t*)take(256 * 512 * 4);
  float* b0c = (float*)take(2048 * 4);
  float* b1c = (float*)take(2048 * 4);
  uint32_t* peg = (uint32_t*)take((size_t)4 * 64 * 512 * 4);
  uint32_t* sg   = (uint32_t*)take(256 * 64 * 4);
  uint32_t* h0g  = (uint32_t*)take(256 * 64 * 4);
  uint32_t* h0gT = (uint32_t*)take(64 * 256 * 4);
  uint32_t* h1ga = (uint32_t*)take(256 * 64 * 4);
  uint32_t* h1gb = (uint32_t*)take(256 * 64 * 4);
  int* bar = (int*)take(8192 * 4);

  float* xp = out;   // d_out doubles as RNN input-projection buffer

  prep_kernel<<<256, 256, 0, stream>>>(att_w1, l0_bih, l0_bhh, l1_bih, l1_bhh,
                                       wsT, b0c, b1c, bar);
  xpose_x<<<dim3(512, 8), 256, 0, stream>>>(x, xt);

  gemm_bias<false,0><<<dim3(256, 8), 256, 0, stream>>>(
      x, rnn_wif, 512, rnn_wib, 512, 256, rnn_bif, rnn_bib, (void*)xp, 32768, 512, 512);

  rnn_scan<<<128, 512, 0, stream>>>(xp, rnn_whf, rnn_whb, rnn_bhf, rnn_bhb, hctx);

  xpose_h<<<dim3(64, 8, 8), 256, 0, stream>>>(hctx, h8T);

  gemm_bias<true,2><<<dim3(256, 8), 256, 0, stream>>>(
      hctx, att_w1 + 512, 1024, nullptr, 1024, 512, att_b1, nullptr, (void*)ph8, 32768, 512, 512);

  {
    const uint8_t* ph_c = ph8; const uint8_t* h8T_c = h8T;
    const uint32_t* xt_c = xt; const uint32_t* wsT_c = wsT;
    const float *w0i = l0_wih, *w0h = l0_whh, *w1i = l1_wih, *w1h = l1_whh;
    const float *b0c_c = b0c, *b1c_c = b1c, *aw2 = att_w2, *ab2 = att_b2;
    float *out_ = out;
    uint32_t *peg_ = peg, *sg_ = sg, *h0g_ = h0g, *h0gT_ = h0gT, *h1ga_ = h1ga, *h1gb_ = h1gb;
    int* bar_ = bar;
    void* args[] = {
      (void*)&ph_c, (void*)&h8T_c, (void*)&xt_c, (void*)&wsT_c,
      (void*)&w0i, (void*)&w0h, (void*)&w1i, (void*)&w1h,
      (void*)&b0c_c, (void*)&b1c_c, (void*)&aw2, (void*)&ab2,
      (void*)&peg_, (void*)&sg_, (void*)&h0g_, (void*)&h0gT_, (void*)&h1ga_, (void*)&h1gb_,
      (void*)&out_, (void*)&bar_
    };
    hipLaunchCooperativeKernel((void*)main_loop, dim3(256), dim3(1024), args, 0, stream);
  }
}

// Round 11
// 15821.649 us; speedup vs baseline: 2.0904x; 1.7627x over previous
//
#include <hip/hip_runtime.h>
#include <hip/hip_fp16.h>
#include <stdint.h>

#define TT 512
#define BB 64
#define DD 512

// ---------- helpers ----------
typedef _Float16 h2v __attribute__((ext_vector_type(2)));
union H2U { uint32_t u; h2v h; };

__device__ __forceinline__ float bfl(uint32_t u){ return __uint_as_float(u << 16); }
__device__ __forceinline__ float bfh(uint32_t u){ return __uint_as_float(u & 0xffff0000u); }
__device__ __forceinline__ float bf2f(uint16_t u){ return __uint_as_float(((uint32_t)u) << 16); }
__device__ __forceinline__ float u2f(uint32_t u){ return __uint_as_float(u); }
__device__ __forceinline__ uint16_t f2bf(float f){
  uint32_t u = __float_as_uint(f);
  u += 0x7fffu + ((u >> 16) & 1u);
  return (uint16_t)(u >> 16);
}
__device__ __forceinline__ uint32_t packbf(float a, float b){
  return (uint32_t)f2bf(a) | ((uint32_t)f2bf(b) << 16);
}
// f16 pack/unpack (cvt_pkrtz returns __fp16x2 -> bit-copy, don't type-pun assign)
__device__ __forceinline__ uint32_t packh(float a, float b){
  auto v = __builtin_amdgcn_cvt_pkrtz(a, b);
  uint32_t u;
  __builtin_memcpy(&u, &v, 4);
  return u;
}
__device__ __forceinline__ float h_lo(uint32_t u){ H2U c; c.u = u; return (float)c.h.x; }
__device__ __forceinline__ float h_hi(uint32_t u){ H2U c; c.u = u; return (float)c.h.y; }

#if __has_builtin(__builtin_amdgcn_fdot2)
__device__ __forceinline__ float FDOT2(uint32_t a, uint32_t b, float c){
  H2U x, y; x.u = a; y.u = b;
  return __builtin_amdgcn_fdot2(x.h, y.h, c, false);
}
#else
__device__ __forceinline__ float FDOT2(uint32_t a, uint32_t b, float c){
  return c + h_lo(a) * h_lo(b) + h_hi(a) * h_hi(b);
}
#endif

// clamp-free graceful forms: p=0 -> -1/0; p=inf -> 1/1
__device__ __forceinline__ float fast_tanh(float x){
  float p = __builtin_amdgcn_exp2f(x * 2.8853900817779268f);
  return __builtin_fmaf(-2.f, __builtin_amdgcn_rcpf(p + 1.f), 1.f);
}
__device__ __forceinline__ float fast_sig(float x){
  float p = __builtin_amdgcn_exp2f(x * 1.4426950408889634f);
  return 1.f - __builtin_amdgcn_rcpf(p + 1.f);
}

// ---------- fp8 e4m3fn pack/unpack (HW on gfx950; SW fallback) ----------
#if __has_builtin(__builtin_amdgcn_cvt_pk_f32_fp8) && __has_builtin(__builtin_amdgcn_cvt_pk_fp8_f32)
#define HWFP8 1
typedef float f32x2_t __attribute__((ext_vector_type(2)));
#endif

__device__ __forceinline__ float fp8_dec1(uint32_t v){
  uint32_t em = v & 0x7f, sg = (v >> 7) << 31;
  float nf = __uint_as_float(sg | (((em >> 3) + 120) << 23) | ((em & 7) << 20));
  float sf = __uint_as_float(sg | 0x3B000000u) * (float)(em & 7);
  return (em >> 3) ? nf : sf;
}
__device__ __forceinline__ uint32_t fp8_enc1(float f){
  uint32_t u = __float_as_uint(f);
  uint32_t sg = (u >> 31) << 7;
  uint32_t e = (u >> 23) & 0xff;
  if (e >= 121){
    u += 0x7ffff + ((u >> 20) & 1);
    e = (u >> 23) & 0xff;
    uint32_t m = (u >> 20) & 7;
    uint32_t e8 = e - 120;
    if (e8 > 15){ e8 = 15; m = 6; }
    return sg | (e8 << 3) | m;
  }
  float af = __uint_as_float(u & 0x7fffffffu);
  uint32_t m = (uint32_t)__builtin_rintf(af * 512.f);
  if (m >= 8) return sg | 0x08u;
  return sg | m;
}
__device__ __forceinline__ void fp8x4_dec(uint32_t w, float* o){
#ifdef HWFP8
  f32x2_t lo = __builtin_amdgcn_cvt_pk_f32_fp8((int)w, false);
  f32x2_t hi = __builtin_amdgcn_cvt_pk_f32_fp8((int)w, true);
  o[0] = lo.x; o[1] = lo.y; o[2] = hi.x; o[3] = hi.y;
#else
  o[0] = fp8_dec1(w & 0xff); o[1] = fp8_dec1((w >> 8) & 0xff);
  o[2] = fp8_dec1((w >> 16) & 0xff); o[3] = fp8_dec1(w >> 24);
#endif
}
__device__ __forceinline__ uint32_t fp8x4_enc(float a, float b, float c, float d){
#ifdef HWFP8
  int u = __builtin_amdgcn_cvt_pk_fp8_f32(a, b, 0, false);
  u = __builtin_amdgcn_cvt_pk_fp8_f32(c, d, u, true);
  return (uint32_t)u;
#else
  return fp8_enc1(a) | (fp8_enc1(b) << 8) | (fp8_enc1(c) << 16) | (fp8_enc1(d) << 24);
#endif
}

#define SCOPE_AG __HIP_MEMORY_SCOPE_AGENT

// ---- coherent (L2-bypass, L3 coherence point) accessors; ALWAYS full wait ----
__device__ __forceinline__ uint32_t ld32_coh(const uint32_t* p){
  uint32_t r;
  asm volatile("global_load_dword %0, %1, off sc0 sc1\n\ts_waitcnt vmcnt(0)"
               : "=&v"(r) : "v"(p) : "memory");
  return r;
}
__device__ __forceinline__ void ld32x4_coh(const uint32_t* p0, const uint32_t* p1,
                                           const uint32_t* p2, const uint32_t* p3,
                                           uint32_t& a, uint32_t& b,
                                           uint32_t& c, uint32_t& d){
  asm volatile("global_load_dword %0, %4, off sc0 sc1\n\t"
               "global_load_dword %1, %5, off sc0 sc1\n\t"
               "global_load_dword %2, %6, off sc0 sc1\n\t"
               "global_load_dword %3, %7, off sc0 sc1\n\t"
               "s_waitcnt vmcnt(0)"
               : "=&v"(a), "=&v"(b), "=&v"(c), "=&v"(d)
               : "v"(p0), "v"(p1), "v"(p2), "v"(p3) : "memory");
}
__device__ __forceinline__ void ld16x2_coh2(const void* p0, const void* p1,
                                            uint4& a, uint4& b){
  asm volatile("global_load_dwordx4 %0, %2, off sc0 sc1\n\t"
               "global_load_dwordx4 %1, %3, off sc0 sc1\n\t"
               "s_waitcnt vmcnt(0)"
               : "=&v"(a), "=&v"(b) : "v"(p0), "v"(p1) : "memory");
}
__device__ __forceinline__ void ld16x4_coh4(const void* p0, const void* p1,
                                            const void* p2, const void* p3,
                                            uint4& a, uint4& b, uint4& c, uint4& d){
  asm volatile("global_load_dwordx4 %0, %4, off sc0 sc1\n\t"
               "global_load_dwordx4 %1, %5, off sc0 sc1\n\t"
               "global_load_dwordx4 %2, %6, off sc0 sc1\n\t"
               "global_load_dwordx4 %3, %7, off sc0 sc1\n\t"
               "s_waitcnt vmcnt(0)"
               : "=&v"(a), "=&v"(b), "=&v"(c), "=&v"(d)
               : "v"(p0), "v"(p1), "v"(p2), "v"(p3) : "memory");
}
__device__ __forceinline__ void st32_coh(uint32_t* p, uint32_t v){
  asm volatile("global_store_dword %0, %1, off sc0 sc1" :: "v"(p), "v"(v) : "memory");
}
__device__ __forceinline__ void drain_vm(){
  asm volatile("s_waitcnt vmcnt(0)" ::: "memory");
}
__device__ __forceinline__ void spin_neq(int* p, int v){
  while (__hip_atomic_load(p, __ATOMIC_RELAXED, SCOPE_AG) == v)
    __builtin_amdgcn_s_sleep(1);
}

// Two-level grid barrier, 256 WGs, relaxed agent-scope atomics (proven r2/r3/r7/r9).
__device__ void gridbar(int* bar){
  drain_vm();
  __syncthreads();
  if (threadIdx.x == 0){
    int x = blockIdx.x & 7;
    int* scnt = bar + x * 32;
    int* sgen = bar + (8 + x) * 32;
    int* mcnt = bar + 16 * 32;
    int* mgen = bar + 17 * 32;
    int g = __hip_atomic_load(sgen, __ATOMIC_RELAXED, SCOPE_AG);
    int old = __hip_atomic_fetch_add(scnt, 1, __ATOMIC_RELAXED, SCOPE_AG);
    if (old == 31){
      __hip_atomic_store(scnt, 0, __ATOMIC_RELAXED, SCOPE_AG);
      int gm = __hip_atomic_load(mgen, __ATOMIC_RELAXED, SCOPE_AG);
      int om = __hip_atomic_fetch_add(mcnt, 1, __ATOMIC_RELAXED, SCOPE_AG);
      if (om == 7){
        __hip_atomic_store(mcnt, 0, __ATOMIC_RELAXED, SCOPE_AG);
        __hip_atomic_fetch_add(mgen, 1, __ATOMIC_RELAXED, SCOPE_AG);
      } else {
        spin_neq(mgen, gm);
      }
      __hip_atomic_fetch_add(sgen, 1, __ATOMIC_RELAXED, SCOPE_AG);
    } else {
      spin_neq(sgen, g);
    }
  }
  __syncthreads();
}

// 4-member group barrier (WGs sharing batch element b: wg = b + 64k).
__device__ __forceinline__ void groupbar(int* bar, int gid){
  drain_vm();
  __syncthreads();
  if (threadIdx.x == 0){
    int* c = bar + (32 + gid) * 32;
    int* g = bar + (96 + gid) * 32;
    int gv = __hip_atomic_load(g, __ATOMIC_RELAXED, SCOPE_AG);
    int old = __hip_atomic_fetch_add(c, 1, __ATOMIC_RELAXED, SCOPE_AG);
    if (old == 3){
      __hip_atomic_store(c, 0, __ATOMIC_RELAXED, SCOPE_AG);
      __hip_atomic_fetch_add(g, 1, __ATOMIC_RELAXED, SCOPE_AG);
    } else {
      spin_neq(g, gv);
    }
  }
  __syncthreads();
}

// ---------- K0: conversions / init ----------
__global__ void prep_kernel(
  const float* __restrict__ att_w1,
  const float* __restrict__ l0_bih, const float* __restrict__ l0_bhh,
  const float* __restrict__ l1_bih, const float* __restrict__ l1_bhh,
  uint32_t* __restrict__ wsT, float* __restrict__ b0c, float* __restrict__ b1c,
  int* __restrict__ bar)
{
  int stride = gridDim.x * blockDim.x;
  int i0 = blockIdx.x * blockDim.x + threadIdx.x;
  for (int i = i0; i < 256*512; i += stride){
    int k2 = i >> 9, j = i & 511;
    wsT[i] = packh(att_w1[(size_t)j*1024 + 2*k2], att_w1[(size_t)j*1024 + 2*k2 + 1]);
  }
  for (int i = i0; i < 2048; i += stride){
    b0c[i] = l0_bih[i] + l0_bhh[i];
    b1c[i] = l1_bih[i] + l1_bhh[i];
  }
  for (int i = i0; i < 8192; i += stride) bar[i] = 0;
}

// ---------- K0b: x[t][b][k] f32 -> xt[t][k2][b] f16-pairs ----------
__global__ __launch_bounds__(256) void xpose_x(const float* __restrict__ x,
                                               uint32_t* __restrict__ xt)
{
  __shared__ float tile[64][65];
  int t = blockIdx.x, kb = blockIdx.y;
  int r = threadIdx.x >> 2, c0 = (threadIdx.x & 3) * 16;
  const float* src = x + ((size_t)t*64 + r)*512 + kb*64 + c0;
  #pragma unroll
  for (int i = 0; i < 16; i += 4)
    *(float4*)&tile[r][c0 + i] = *(const float4*)(src + i);
  __syncthreads();
  int b = threadIdx.x & 63, k2l0 = threadIdx.x >> 6;
  for (int k2l = k2l0; k2l < 32; k2l += 4)
    xt[((size_t)t*256 + kb*32 + k2l)*64 + b] = packh(tile[b][k2l*2], tile[b][k2l*2+1]);
}

// ---------- K2b: hctx[t][b][d] -> h8T[b][d][t] (fp8 e4m3) ----------
__global__ __launch_bounds__(256) void xpose_h(const uint16_t* __restrict__ hctx,
                                               uint8_t* __restrict__ h8T)
{
  __shared__ uint16_t tile[64][72];
  int b = blockIdx.x, tb = blockIdx.y, db = blockIdx.z;
  int tl = threadIdx.x >> 2, c0 = (threadIdx.x & 3) * 16;
  const uint16_t* src = hctx + ((size_t)(tb*64 + tl)*64 + b)*512 + db*64 + c0;
  *(uint4*)&tile[tl][c0]     = *(const uint4*)src;
  *(uint4*)&tile[tl][c0 + 8] = *(const uint4*)(src + 8);
  __syncthreads();
  int dl = threadIdx.x >> 2, t0 = (threadIdx.x & 3) * 16;
  uint16_t tmp[16];
  #pragma unroll
  for (int i = 0; i < 16; ++i) tmp[i] = tile[t0 + i][dl];
  uint32_t o[4];
  #pragma unroll
  for (int k = 0; k < 4; ++k)
    o[k] = fp8x4_enc(bf2f(tmp[k*4]), bf2f(tmp[k*4+1]), bf2f(tmp[k*4+2]), bf2f(tmp[k*4+3]));
  uint8_t* dst = h8T + ((size_t)b*512 + db*64 + dl)*512 + tb*64 + t0;
  *(uint4*)dst = make_uint4(o[0], o[1], o[2], o[3]);
}

// ---------- K1/K3: C = A @ B^T + bias ----------
// OMODE: 0 = f32 row-major, 2 = fp8 ph-layout [kq*64+b][tt][128]
template<bool ABF, int OMODE>
__global__ __launch_bounds__(256) void gemm_bias(
  const void* __restrict__ A_, const float* __restrict__ B0, int ldb0,
  const float* __restrict__ B1, int ldb1, int nsplit,
  const float* __restrict__ bias0, const float* __restrict__ bias1,
  void* __restrict__ C_, int M, int N, int K)
{
  __shared__ float As[16][132];
  __shared__ float Bs[16][68];
  const int bm = blockIdx.x * 128, bn = blockIdx.y * 64;
  const int tid = threadIdx.x;
  const int m0 = (tid >> 4) * 8, n0 = (tid & 15) * 4;
  float acc[8][4] = {};
  for (int k0 = 0; k0 < K; k0 += 16){
    {
      int r = tid >> 1, c = (tid & 1) * 8;
      if (ABF){
        const uint16_t* ap = (const uint16_t*)A_ + (size_t)(bm + r) * K + k0 + c;
        uint4 v = *(const uint4*)ap;
        const uint16_t* pv = (const uint16_t*)&v;
        #pragma unroll
        for (int i = 0; i < 8; ++i) As[c + i][r] = bf2f(pv[i]);
      } else {
        const float* ap = (const float*)A_ + (size_t)(bm + r) * K + k0 + c;
        float4 v0 = *(const float4*)ap, v1 = *(const float4*)(ap + 4);
        As[c+0][r] = v0.x; As[c+1][r] = v0.y; As[c+2][r] = v0.z; As[c+3][r] = v0.w;
        As[c+4][r] = v1.x; As[c+5][r] = v1.y; As[c+6][r] = v1.z; As[c+7][r] = v1.w;
      }
    }
    {
      int n = tid >> 2, cc = (tid & 3) * 4;
      int gn = bn + n;
      const float* bp = (gn < nsplit) ? (B0 + (size_t)gn * ldb0 + k0 + cc)
                                      : (B1 + (size_t)(gn - nsplit) * ldb1 + k0 + cc);
      float4 v = *(const float4*)bp;
      Bs[cc+0][n] = v.x; Bs[cc+1][n] = v.y; Bs[cc+2][n] = v.z; Bs[cc+3][n] = v.w;
    }
    __syncthreads();
    #pragma unroll
    for (int k = 0; k < 16; ++k){
      float a[8], bv[4];
      #pragma unroll
      for (int i = 0; i < 8; ++i) a[i] = As[k][m0 + i];
      #pragma unroll
      for (int j = 0; j < 4; ++j) bv[j] = Bs[k][n0 + j];
      #pragma unroll
      for (int i = 0; i < 8; ++i)
        #pragma unroll
        for (int j = 0; j < 4; ++j) acc[i][j] += a[i] * bv[j];
    }
    __syncthreads();
  }
  #pragma unroll
  for (int i = 0; i < 8; ++i){
    int gm = bm + m0 + i;
    if (OMODE == 2){
      float vv[4];
      #pragma unroll
      for (int j = 0; j < 4; ++j){
        int gn = bn + n0 + j;
        float bias = (gn < nsplit) ? bias0[gn] : bias1[gn - nsplit];
        vv[j] = acc[i][j] + bias;
      }
      int gn0 = bn + n0;
      size_t idx = ((size_t)((gn0 >> 7) * 64 + (gm & 63)) * 512 + (gm >> 6)) * 128
                 + (gn0 & 127);
      *(uint32_t*)((uint8_t*)C_ + idx) = fp8x4_enc(vv[0], vv[1], vv[2], vv[3]);
    } else {
      #pragma unroll
      for (int j = 0; j < 4; ++j){
        int gn = bn + n0 + j;
        float bias = (gn < nsplit) ? bias0[gn] : bias1[gn - nsplit];
        ((float*)C_)[(size_t)gm * N + gn] = acc[i][j] + bias;
      }
    }
  }
}

// ---------- K2: bi-RNN scan ----------
__global__ __launch_bounds__(512) void rnn_scan(
  const float* __restrict__ xp, const float* __restrict__ whf,
  const float* __restrict__ whb, const float* __restrict__ bhf,
  const float* __restrict__ bhb, uint16_t* __restrict__ hctx)
{
  __shared__ float hbuf[256];
  __shared__ float partial[512];
  const int wg = blockIdx.x, dir = wg >> 6, b = wg & 63, tid = threadIdx.x;
  const int j = tid & 255, half = tid >> 8;
  const float* wh = dir ? whb : whf;
  const float bj = (dir ? bhb : bhf)[j];
  uint32_t wreg[64];
  #pragma unroll
  for (int m = 0; m < 64; ++m){
    int k = half * 128 + m * 2;
    wreg[m] = packbf(wh[j * 256 + k], wh[j * 256 + k + 1]);
  }
  if (tid < 256) hbuf[tid] = 0.f;
  __syncthreads();
  for (int step = 0; step < TT; ++step){
    int t = dir ? (TT - 1 - step) : step;
    float acc = 0.f;
    const float* hb = hbuf + half * 128;
    #pragma unroll 16
    for (int m = 0; m < 64; ++m){
      uint32_t w = wreg[m];
      acc += bfl(w) * hb[m * 2] + bfh(w) * hb[m * 2 + 1];
    }
    partial[tid] = acc;
    __syncthreads();
    if (tid < 256){
      float v = partial[tid] + partial[tid + 256]
              + xp[(size_t)(t * 64 + b) * 512 + dir * 256 + j] + bj;
      v = fast_tanh(v);
      hbuf[j] = v;
      hctx[(size_t)(t * 64 + b) * 512 + dir * 256 + j] = f2bf(v);
    }
    __syncthreads();
  }
}

// ---------- LSTM inner dot via v_dot2_f32_f16: 16 k2 rows of [128 k2][64 b] ----------
__device__ __forceinline__ void lstm_dot(
  const uint32_t* __restrict__ tXl, const uint32_t* __restrict__ tSl,
  const uint32_t* __restrict__ wlp,   // [16 rows][256 pairs] f16x2
  int ch, int b, int ul, int q8, float* acc)
{
  #pragma unroll 8
  for (int pp = 0; pp < 8; ++pp){
    int k2l = q8 * 16 + pp * 2;
    uint32_t xv0 = tXl[k2l * 64 + b];
    uint32_t xv1 = tXl[(k2l + 1) * 64 + b];
    uint32_t sv0 = tSl[k2l * 64 + b];
    uint32_t sv1 = tSl[(k2l + 1) * 64 + b];
    const uint32_t* wb = wlp + ul * 256 + ch * 128 + k2l;
    #pragma unroll
    for (int g = 0; g < 4; ++g){
      uint2 wi = *(const uint2*)(wb + (g * 2) * 256);
      uint2 wh = *(const uint2*)(wb + (8 + g * 2) * 256);
      acc[g] = FDOT2(xv0, wi.x, acc[g]);
      acc[g] = FDOT2(xv1, wi.y, acc[g]);
      acc[g] = FDOT2(sv0, wh.x, acc[g]);
      acc[g] = FDOT2(sv1, wh.y, acc[g]);
    }
  }
}

// ---------- LSTM gate phase (1024 threads); lane-consecutive 16B staging ----------
template<bool XCOH>
__device__ __forceinline__ void lstm_phase(
  const uint32_t* __restrict__ xin,   // [256 k2][64 b] f16 pairs (plain if !XCOH)
  const uint32_t* __restrict__ hin,   // [256 k2][64 b] f16 pairs (coherent)
  const uint32_t* __restrict__ wlp, const float* __restrict__ bias8,
  float& cs0, float& cs1,
  uint32_t* __restrict__ hog,         // [256][64] pair out, row = wgid
  uint32_t* __restrict__ hogT,        // optional [64 b][256 k2] transposed copy
  float* __restrict__ outp,           // optional out + t*32768
  uint32_t* tX, uint32_t* tS, float* part, float* glds,
  int u0, int tid, int wgid)
{
  const int b = tid & 63, ul = (tid >> 6) & 1, q8 = tid >> 7;
  float acc[4] = {0.f, 0.f, 0.f, 0.f};
  #pragma unroll 1
  for (int ch = 0; ch < 2; ++ch){
    {
      const uint32_t* xs = xin + ch * 8192;
      const uint32_t* hs = hin + ch * 8192;
      uint4 a0, a1, c0, c1;
      if (XCOH){
        ld16x4_coh4(xs + tid * 4, xs + 4096 + tid * 4,
                    hs + tid * 4, hs + 4096 + tid * 4, a0, a1, c0, c1);
      } else {
        a0 = *(const uint4*)(xs + tid * 4);
        a1 = *(const uint4*)(xs + 4096 + tid * 4);
        ld16x2_coh2(hs + tid * 4, hs + 4096 + tid * 4, c0, c1);
      }
      *(uint4*)(tX + tid * 4)        = a0;
      *(uint4*)(tX + 4096 + tid * 4) = a1;
      *(uint4*)(tS + tid * 4)        = c0;
      *(uint4*)(tS + 4096 + tid * 4) = c1;
    }
    __syncthreads();
    lstm_dot(tX, tS, wlp, ch, b, ul, q8, acc);
    __syncthreads();
  }
  #pragma unroll
  for (int g = 0; g < 4; ++g) part[((g * 2 + ul) * 8 + q8) * 64 + b] = acc[g];
  __syncthreads();
  if (tid < 512){
    int g = tid >> 7, uu = (tid >> 6) & 1, bb = tid & 63;
    float s = bias8[g * 2 + uu];
    #pragma unroll
    for (int i = 0; i < 8; ++i) s += part[((g * 2 + uu) * 8 + i) * 64 + bb];
    glds[(g * 2 + uu) * 64 + bb] = s;
  }
  __syncthreads();
  if (tid < 64){
    float gi0 = glds[0 * 64 + tid], gi1 = glds[1 * 64 + tid];
    float gf0 = glds[2 * 64 + tid], gf1 = glds[3 * 64 + tid];
    float gg0 = glds[4 * 64 + tid], gg1 = glds[5 * 64 + tid];
    float go0 = glds[6 * 64 + tid], go1 = glds[7 * 64 + tid];
    float c0 = fast_sig(gf0) * cs0 + fast_sig(gi0) * fast_tanh(gg0);
    float c1 = fast_sig(gf1) * cs1 + fast_sig(gi1) * fast_tanh(gg1);
    cs0 = c0; cs1 = c1;
    float h0v = fast_sig(go0) * fast_tanh(c0);
    float h1v = fast_sig(go1) * fast_tanh(c1);
    uint32_t pr = packh(h0v, h1v);
    st32_coh(hog + wgid * 64 + tid, pr);
    if (hogT) st32_coh(hogT + tid * 256 + wgid, pr);
    if (outp) *(float2*)(outp + (size_t)tid * 512 + u0) = make_float2(h0v, h1v);
  }
  __syncthreads();
}

// ---------- K4: persistent fused main scan (256 WGs x 1024 threads, coop) ----------
// Per step: A0+A1 -> peg store -> LSTM1(t-1) [hides groupbar] -> groupbar ->
//           A2+A3 -> s store -> S1 -> LSTM0(t) -> S2
__global__ __launch_bounds__(1024) void main_loop(
  const uint8_t* __restrict__ ph8,     // [kq*64+b][tt][128] fp8
  const uint8_t* __restrict__ h8T,     // [b][d][tt] fp8
  const uint32_t* __restrict__ xt,     // [t][256][64] f16 pairs
  const uint32_t* __restrict__ wsT,    // [256 k2][512 j] f16 pairs
  const float* __restrict__ w0i, const float* __restrict__ w0h,
  const float* __restrict__ w1i, const float* __restrict__ w1h,
  const float* __restrict__ b0c, const float* __restrict__ b1c,
  const float* __restrict__ attw2, const float* __restrict__ attb2,
  uint32_t* __restrict__ peg,          // [4 kq][64 b][512 tt] f32 partial-e
  uint32_t* __restrict__ sg, uint32_t* __restrict__ h0g,
  uint32_t* __restrict__ h0gT,         // [64 b][256 k2] pairs
  uint32_t* __restrict__ h1ga, uint32_t* __restrict__ h1gb,
  float* __restrict__ out, int* bar)
{
  __shared__ __align__(16) uint32_t wl0p[16 * 256];    // 16KB L0 weights f16-pairs
  __shared__ __align__(16) uint32_t wl1p[16 * 256];    // 16KB L1 weights f16-pairs
  __shared__ __align__(16) uint32_t tX[128 * 64];      // 32KB LSTM arena A
  __shared__ __align__(16) uint32_t tS[128 * 64];      // 32KB LSTM arena B
  __shared__ float glds[512];
  // dedicated attention arena — survives across LSTM1 interleave
  __shared__ float hldf[512];
  __shared__ uint32_t hp2[256];
  __shared__ float qloc[128];
  __shared__ float eldf[8 * 66];
  __shared__ float qpart[128 * 9];
  __shared__ float spart[512 * 3];
  __shared__ float w2loc[128];
  __shared__ float w2s[2];
  __shared__ float bias0l[8], bias1l[8];
  __shared__ float zsh[1];

  const int wg = blockIdx.x, tid = threadIdx.x;
  const int b_att = wg & 63, kq = wg >> 6;
  const int u0 = wg * 2;
  float* spart2 = spart;   // reuse after spart consumed
  float* part = (float*)tX;

  // ---- one-time LDS loads (weights packed f16) ----
  {
    int r = tid >> 6, c = (tid & 63) * 8;
    int rr = r & 7, g = rr >> 1, uu = rr & 1;
    const float* s0 = ((r < 8) ? w0i : w0h) + ((size_t)(g * 512 + u0 + uu)) * 512 + c;
    float4 v0 = *(const float4*)s0, v1 = *(const float4*)(s0 + 4);
    wl0p[r * 256 + (c >> 1) + 0] = packh(v0.x, v0.y);
    wl0p[r * 256 + (c >> 1) + 1] = packh(v0.z, v0.w);
    wl0p[r * 256 + (c >> 1) + 2] = packh(v1.x, v1.y);
    wl0p[r * 256 + (c >> 1) + 3] = packh(v1.z, v1.w);
    const float* s1 = ((r < 8) ? w1i : w1h) + ((size_t)(g * 512 + u0 + uu)) * 512 + c;
    float4 w0 = *(const float4*)s1, w1 = *(const float4*)(s1 + 4);
    wl1p[r * 256 + (c >> 1) + 0] = packh(w0.x, w0.y);
    wl1p[r * 256 + (c >> 1) + 1] = packh(w0.z, w0.w);
    wl1p[r * 256 + (c >> 1) + 2] = packh(w1.x, w1.y);
    wl1p[r * 256 + (c >> 1) + 3] = packh(w1.z, w1.w);
  }
  if (tid < 128) w2loc[tid] = -2.f * attw2[kq * 128 + tid];
  if (tid >= 128 && tid < 130){
    int h = tid - 128; float s = 0.f;
    for (int i = 0; i < 64; ++i) s += attw2[kq * 128 + h * 64 + i];
    w2s[h] = s;
  }
  if (tid < 8){
    int g = tid >> 1, uu = tid & 1;
    bias0l[tid] = b0c[g * 512 + u0 + uu];
    bias1l[tid] = b1c[g * 512 + u0 + uu];
  }
  const float b2s = attb2[0];
  float c0s0 = 0.f, c0s1 = 0.f, c1s0 = 0.f, c1s1 = 0.f;

  // zero shared-state buffers (visible after first gridbar)
  {
    int idx = wg * 1024 + tid;
    if (idx < 256 * 64){
      st32_coh(sg + idx, 0); st32_coh(h0g + idx, 0);
      st32_coh(h1ga + idx, 0); st32_coh(h1gb + idx, 0);
    }
  }
  __syncthreads();

  #pragma unroll 1
  for (int t = 0; t < TT; ++t){
    if (t > 0){
      // ---- A0: stage h0[b_att] (coalesced h0gT) + q quarter GEMV via fdot2 ----
      if (tid < 256){
        uint32_t v = ld32_coh(h0gT + b_att * 256 + tid);
        hp2[tid] = v;
        hldf[tid * 2] = h_lo(v); hldf[tid * 2 + 1] = h_hi(v);
      }
      __syncthreads();
      {
        int jl = tid & 127, kseg = tid >> 7;
        const uint32_t* wp = wsT + (size_t)(kseg * 32) * 512 + kq * 128 + jl;
        const uint32_t* hp = hp2 + kseg * 32;
        float acc = 0.f;
        #pragma unroll 8
        for (int i = 0; i < 32; ++i)
          acc = FDOT2(wp[(size_t)i * 512], hp[i], acc);
        qpart[jl * 9 + kseg] = acc;
      }
      __syncthreads();
      if (tid < 128){
        float s = 0.f;
        #pragma unroll
        for (int i = 0; i < 8; ++i) s += qpart[tid * 9 + i];
        qloc[tid] = s;
      }
      __syncthreads();
      // ---- A1: partial scores over ALL 512 tt, contiguous fp8 ph slice ----
      {
        int ttl = tid >> 1, dseg = tid & 1;
        const uint8_t* pb = ph8 + (((size_t)(kq * 64 + b_att) * 512) + ttl) * 128
                                + dseg * 64;
        uint4 vv[4];
        #pragma unroll
        for (int i = 0; i < 4; ++i) vv[i] = ((const uint4*)pb)[i];
        const float* qp = qloc + dseg * 64;
        const float* wp = w2loc + dseg * 64;
        const uint32_t* wu = (const uint32_t*)vv;
        float acc = 0.f;
        #pragma unroll
        for (int i = 0; i < 16; ++i){
          float f4[4];
          fp8x4_dec(wu[i], f4);
          #pragma unroll
          for (int j = 0; j < 4; ++j){
            float z = f4[j] + qp[i * 4 + j];
            float pw = __builtin_amdgcn_exp2f(z * 2.8853900817779268f);
            acc = __builtin_fmaf(wp[i * 4 + j], __builtin_amdgcn_rcpf(pw + 1.f), acc);
          }
        }
        spart[ttl * 3 + dseg] = acc;
      }
      __syncthreads();
      if (tid < 512){   // contiguous 2KB store per WG
        float s = spart[tid * 3] + spart[tid * 3 + 1] + w2s[0] + w2s[1];
        st32_coh(peg + ((size_t)(kq * 64 + b_att)) * 512 + tid, __float_as_uint(s));
      }
      // ---- LSTM1 for step t-1: overlaps peg drain + sibling skew ----
      {
        int tau = t - 1;
        const uint32_t* h1rd = (tau & 1) ? h1gb : h1ga;
        uint32_t* h1wr = (tau & 1) ? h1ga : h1gb;
        lstm_phase<true>(h0g, h1rd, wl1p, bias1l, c1s0, c1s1,
                         h1wr, nullptr, out + (size_t)tau * (64 * 512),
                         tX, tS, part, glds, u0, tid, wg);
      }
      groupbar(bar, b_att);
      // ---- A2: e finalize (4 batched coh loads, 1 wait) + Z ----
      if (tid < 512){
        uint32_t e0, e1, e2, e3;
        const uint32_t* pg = peg + (size_t)b_att * 512 + tid;
        ld32x4_coh(pg, pg + 32768, pg + 65536, pg + 98304, e0, e1, e2, e3);
        float s = u2f(e0) + u2f(e1) + u2f(e2) + u2f(e3) + b2s;
        float e = fast_tanh(s);
        eldf[(tid >> 6) * 66 + (tid & 63)] = __builtin_amdgcn_exp2f(e * 1.4426950408889634f);
      }
      __syncthreads();
      if (tid < 64){
        float zp = 0.f;
        #pragma unroll
        for (int k = 0; k < 8; ++k) zp += eldf[k * 66 + tid];
        #pragma unroll
        for (int m = 32; m; m >>= 1) zp += __shfl_xor(zp, m);
        if (tid == 0) zsh[0] = __builtin_amdgcn_rcpf(zp);
      }
      // ---- A3: ctx partial (own 128-d slice, all tt, fp8) ----
      {
        int dl = tid >> 3, tseg = tid & 7;
        const uint8_t* hb = h8T + ((size_t)b_att * 512 + kq * 128 + dl) * 512 + tseg * 64;
        uint4 vv[4];
        #pragma unroll
        for (int i = 0; i < 4; ++i) vv[i] = ((const uint4*)hb)[i];
        const float* ep = eldf + tseg * 66;
        const uint32_t* wu = (const uint32_t*)vv;
        float acc = 0.f;
        #pragma unroll
        for (int i = 0; i < 16; ++i){
          float f4[4];
          fp8x4_dec(wu[i], f4);
          #pragma unroll
          for (int j = 0; j < 4; ++j)
            acc = __builtin_fmaf(ep[i * 4 + j], f4[j], acc);
        }
        __syncthreads();     // spart consumed; safe to reuse
        spart2[dl * 9 + tseg] = acc;
      }
      __syncthreads();
      if (tid < 64){
        float cv0 = 0.f, cv1 = 0.f;
        #pragma unroll
        for (int i = 0; i < 8; ++i){
          cv0 += spart2[(2 * tid) * 9 + i];
          cv1 += spart2[(2 * tid + 1) * 9 + i];
        }
        float rz = zsh[0];
        float s0 = hldf[kq * 128 + 2 * tid]     + cv0 * rz;
        float s1 = hldf[kq * 128 + 2 * tid + 1] + cv1 * rz;
        st32_coh(sg + (kq * 64 + tid) * 64 + b_att, packh(s0, s1));
      }
    }
    gridbar(bar);   // S1: s(t) visible grid-wide
    lstm_phase<false>(xt + (size_t)t * 16384, sg, wl0p, bias0l, c0s0, c0s1,
                      h0g, h0gT, nullptr, tX, tS, part, glds, u0, tid, wg);
    gridbar(bar);   // S2: h0(t) visible grid-wide
  }
  // epilogue: LSTM1 for step 511 (511 & 1 = 1 -> read h1gb)
  lstm_phase<true>(h0g, h1gb, wl1p, bias1l, c1s0, c1s1,
                   h1ga, nullptr, out + (size_t)(TT - 1) * (64 * 512),
                   tX, tS, part, glds, u0, tid, wg);
}

// ---------- host ----------
extern "C" void kernel_launch(void* const* d_in, const int* in_sizes, int n_in,
                              void* d_out, int out_size, void* d_ws, size_t ws_size,
                              hipStream_t stream)
{
  (void)in_sizes; (void)n_in; (void)out_size; (void)ws_size;
  const float* x       = (const float*)d_in[0];
  const float* rnn_wif = (const float*)d_in[1];
  const float* rnn_whf = (const float*)d_in[2];
  const float* rnn_bif = (const float*)d_in[3];
  const float* rnn_bhf = (const float*)d_in[4];
  const float* rnn_wib = (const float*)d_in[5];
  const float* rnn_whb = (const float*)d_in[6];
  const float* rnn_bib = (const float*)d_in[7];
  const float* rnn_bhb = (const float*)d_in[8];
  const float* att_w1  = (const float*)d_in[9];
  const float* att_b1  = (const float*)d_in[10];
  const float* att_w2  = (const float*)d_in[11];
  const float* att_b2  = (const float*)d_in[12];
  const float* l0_wih  = (const float*)d_in[13];
  const float* l0_whh  = (const float*)d_in[14];
  const float* l0_bih  = (const float*)d_in[15];
  const float* l0_bhh  = (const float*)d_in[16];
  const float* l1_wih  = (const float*)d_in[17];
  const float* l1_whh  = (const float*)d_in[18];
  const float* l1_bih  = (const float*)d_in[19];
  const float* l1_bhh  = (const float*)d_in[20];
  float* out = (float*)d_out;

  char* p = (char*)d_ws;
  auto take = [&](size_t bytes){ char* r = p; p += (bytes + 255) & ~(size_t)255; return r; };
  uint8_t*  ph8   = (uint8_t*)take((size_t)TT * BB * DD);
  uint16_t* hctx  = (uint16_t*)take((size_t)TT * BB * DD * 2);
  uint8_t*  h8T   = (uint8_t*)take((size_t)TT * BB * DD);
  uint32_t* xt    = (uint32_t*)take((size_t)TT * 256 * 64 * 4);
  uint32_t* wsT   = (uint32_t*)take(256 * 512 * 4);
  float* b0c = (float*)take(2048 * 4);
  float* b1c = (float*)take(2048 * 4);
  uint32_t* peg = (uint32_t*)take((size_t)4 * 64 * 512 * 4);
  uint32_t* sg   = (uint32_t*)take(256 * 64 * 4);
  uint32_t* h0g  = (uint32_t*)take(256 * 64 * 4);
  uint32_t* h0gT = (uint32_t*)take(64 * 256 * 4);
  uint32_t* h1ga = (uint32_t*)take(256 * 64 * 4);
  uint32_t* h1gb = (uint32_t*)take(256 * 64 * 4);
  int* bar = (int*)take(8192 * 4);

  float* xp = out;   // d_out doubles as RNN input-projection buffer

  prep_kernel<<<256, 256, 0, stream>>>(att_w1, l0_bih, l0_bhh, l1_bih, l1_bhh,
                                       wsT, b0c, b1c, bar);
  xpose_x<<<dim3(512, 8), 256, 0, stream>>>(x, xt);

  gemm_bias<false,0><<<dim3(256, 8), 256, 0, stream>>>(
      x, rnn_wif, 512, rnn_wib, 512, 256, rnn_bif, rnn_bib, (void*)xp, 32768, 512, 512);

  rnn_scan<<<128, 512, 0, stream>>>(xp, rnn_whf, rnn_whb, rnn_bhf, rnn_bhb, hctx);

  xpose_h<<<dim3(64, 8, 8), 256, 0, stream>>>(hctx, h8T);

  gemm_bias<true,2><<<dim3(256, 8), 256, 0, stream>>>(
      hctx, att_w1 + 512, 1024, nullptr, 1024, 512, att_b1, nullptr, (void*)ph8, 32768, 512, 512);

  {
    const uint8_t* ph_c = ph8; const uint8_t* h8T_c = h8T;
    const uint32_t* xt_c = xt; const uint32_t* wsT_c = wsT;
    const float *w0i = l0_wih, *w0h = l0_whh, *w1i = l1_wih, *w1h = l1_whh;
    const float *b0c_c = b0c, *b1c_c = b1c, *aw2 = att_w2, *ab2 = att_b2;
    float *out_ = out;
    uint32_t *peg_ = peg, *sg_ = sg, *h0g_ = h0g, *h0gT_ = h0gT, *h1ga_ = h1ga, *h1gb_ = h1gb;
    int* bar_ = bar;
    void* args[] = {
      (void*)&ph_c, (void*)&h8T_c, (void*)&xt_c, (void*)&wsT_c,
      (void*)&w0i, (void*)&w0h, (void*)&w1i, (void*)&w1h,
      (void*)&b0c_c, (void*)&b1c_c, (void*)&aw2, (void*)&ab2,
      (void*)&peg_, (void*)&sg_, (void*)&h0g_, (void*)&h0gT_, (void*)&h1ga_, (void*)&h1gb_,
      (void*)&out_, (void*)&bar_
    };
    hipLaunchCooperativeKernel((void*)main_loop, dim3(256), dim3(1024), args, 0, stream);
  }
}